// Round 1
// baseline (1606.525 us; speedup 1.0000x reference)
//
#include <hip/hip_runtime.h>

#define NN 100000
#define NE 1600000
#define NF 64
#define DM 32
#define NG 64
#define NC 10
#define BN_EPS 1e-5f

// ---------------- scatter: agg[dst] += x[src], feature-parallel ----------------
template <int F>
__global__ __launch_bounds__(256) void scatter_k(const float* __restrict__ x,
                                                 const int* __restrict__ ei,
                                                 float* __restrict__ agg) {
    long long tid = (long long)blockIdx.x * 256 + threadIdx.x;
    int e = (int)(tid / F);
    int f = (int)(tid % F);
    if (e < NE) {
        int s = ei[e];
        int d = ei[NE + e];
        atomicAdd(&agg[(long long)d * F + f], x[(long long)s * F + f]);
    }
}

// ---------------- layer 1 MLP: (x+agg)[64] -> relu -> [32] -> relu, + BN stats ----------------
__global__ __launch_bounds__(256) void mlp1_k(const float* __restrict__ x,
                                              const float* __restrict__ agg,
                                              const float* __restrict__ wa,
                                              const float* __restrict__ ba,
                                              const float* __restrict__ wb,
                                              const float* __restrict__ bb,
                                              float* __restrict__ out,
                                              float* __restrict__ stats) {
    __shared__ float sWa[64 * 32];
    __shared__ float sWb[32 * 32];
    __shared__ float sBa[32], sBb[32];
    __shared__ float sSum[4 * 32], sSq[4 * 32];
    int tid = threadIdx.x;
    for (int i = tid; i < 64 * 32; i += 256) sWa[i] = wa[i];
    for (int i = tid; i < 32 * 32; i += 256) sWb[i] = wb[i];
    if (tid < 32) { sBa[tid] = ba[tid]; sBb[tid] = bb[tid]; }
    __syncthreads();

    int node = blockIdx.x * 256 + tid;
    float r[32];
    if (node < NN) {
        float t[32];
#pragma unroll
        for (int j = 0; j < 32; j++) t[j] = sBa[j];
        const float4* xr = reinterpret_cast<const float4*>(x + (long long)node * 64);
        const float4* ar = reinterpret_cast<const float4*>(agg + (long long)node * 64);
        const float4* w4 = reinterpret_cast<const float4*>(sWa);
        for (int k4 = 0; k4 < 16; k4++) {
            float4 xv = xr[k4];
            float4 av = ar[k4];
            float a0 = xv.x + av.x, a1 = xv.y + av.y, a2 = xv.z + av.z, a3 = xv.w + av.w;
            int kb = k4 * 4;
#pragma unroll
            for (int q = 0; q < 8; q++) {
                float4 w0 = w4[(kb + 0) * 8 + q];
                float4 w1 = w4[(kb + 1) * 8 + q];
                float4 w2 = w4[(kb + 2) * 8 + q];
                float4 w3 = w4[(kb + 3) * 8 + q];
                t[4 * q + 0] += a0 * w0.x + a1 * w1.x + a2 * w2.x + a3 * w3.x;
                t[4 * q + 1] += a0 * w0.y + a1 * w1.y + a2 * w2.y + a3 * w3.y;
                t[4 * q + 2] += a0 * w0.z + a1 * w1.z + a2 * w2.z + a3 * w3.z;
                t[4 * q + 3] += a0 * w0.w + a1 * w1.w + a2 * w2.w + a3 * w3.w;
            }
        }
#pragma unroll
        for (int j = 0; j < 32; j++) t[j] = fmaxf(t[j], 0.f);
#pragma unroll
        for (int j = 0; j < 32; j++) r[j] = sBb[j];
        const float4* v4 = reinterpret_cast<const float4*>(sWb);
        for (int k = 0; k < 32; k++) {
            float a = t[k];
#pragma unroll
            for (int q = 0; q < 8; q++) {
                float4 w = v4[k * 8 + q];
                r[4 * q + 0] += a * w.x;
                r[4 * q + 1] += a * w.y;
                r[4 * q + 2] += a * w.z;
                r[4 * q + 3] += a * w.w;
            }
        }
#pragma unroll
        for (int j = 0; j < 32; j++) r[j] = fmaxf(r[j], 0.f);
        float4* orow = reinterpret_cast<float4*>(out + (long long)node * 32);
#pragma unroll
        for (int q = 0; q < 8; q++) {
            float4 o;
            o.x = r[4 * q]; o.y = r[4 * q + 1]; o.z = r[4 * q + 2]; o.w = r[4 * q + 3];
            orow[q] = o;
        }
    } else {
#pragma unroll
        for (int j = 0; j < 32; j++) r[j] = 0.f;
    }

    // BN stats: per-feature sum and sumsq across nodes
    int lane = tid & 63, wid = tid >> 6;
#pragma unroll
    for (int j = 0; j < 32; j++) {
        float v = r[j], v2 = v * v;
#pragma unroll
        for (int off = 32; off >= 1; off >>= 1) {
            v += __shfl_down(v, off, 64);
            v2 += __shfl_down(v2, off, 64);
        }
        if (lane == 0) { sSum[wid * 32 + j] = v; sSq[wid * 32 + j] = v2; }
    }
    __syncthreads();
    if (tid < 32) {
        float a = sSum[tid] + sSum[32 + tid] + sSum[64 + tid] + sSum[96 + tid];
        float b = sSq[tid] + sSq[32 + tid] + sSq[64 + tid] + sSq[96 + tid];
        atomicAdd(&stats[tid], a);
        atomicAdd(&stats[32 + tid], b);
    }
}

// ---------------- layers 2-5 MLP: (h+agg)[32] -> relu -> [32] -> relu, + BN stats ----------------
__global__ __launch_bounds__(256) void mlp32_k(const float* __restrict__ hin,
                                               const float* __restrict__ agg,
                                               const float* __restrict__ wa,
                                               const float* __restrict__ ba,
                                               const float* __restrict__ wb,
                                               const float* __restrict__ bb,
                                               float* __restrict__ out,
                                               float* __restrict__ stats) {
    __shared__ float sWa[32 * 32];
    __shared__ float sWb[32 * 32];
    __shared__ float sBa[32], sBb[32];
    __shared__ float sSum[4 * 32], sSq[4 * 32];
    int tid = threadIdx.x;
    for (int i = tid; i < 32 * 32; i += 256) { sWa[i] = wa[i]; sWb[i] = wb[i]; }
    if (tid < 32) { sBa[tid] = ba[tid]; sBb[tid] = bb[tid]; }
    __syncthreads();

    int node = blockIdx.x * 256 + tid;
    float r[32];
    if (node < NN) {
        float t[32];
#pragma unroll
        for (int j = 0; j < 32; j++) t[j] = sBa[j];
        const float4* hr = reinterpret_cast<const float4*>(hin + (long long)node * 32);
        const float4* ar = reinterpret_cast<const float4*>(agg + (long long)node * 32);
        const float4* w4 = reinterpret_cast<const float4*>(sWa);
        for (int k4 = 0; k4 < 8; k4++) {
            float4 xv = hr[k4];
            float4 av = ar[k4];
            float a0 = xv.x + av.x, a1 = xv.y + av.y, a2 = xv.z + av.z, a3 = xv.w + av.w;
            int kb = k4 * 4;
#pragma unroll
            for (int q = 0; q < 8; q++) {
                float4 w0 = w4[(kb + 0) * 8 + q];
                float4 w1 = w4[(kb + 1) * 8 + q];
                float4 w2 = w4[(kb + 2) * 8 + q];
                float4 w3 = w4[(kb + 3) * 8 + q];
                t[4 * q + 0] += a0 * w0.x + a1 * w1.x + a2 * w2.x + a3 * w3.x;
                t[4 * q + 1] += a0 * w0.y + a1 * w1.y + a2 * w2.y + a3 * w3.y;
                t[4 * q + 2] += a0 * w0.z + a1 * w1.z + a2 * w2.z + a3 * w3.z;
                t[4 * q + 3] += a0 * w0.w + a1 * w1.w + a2 * w2.w + a3 * w3.w;
            }
        }
#pragma unroll
        for (int j = 0; j < 32; j++) t[j] = fmaxf(t[j], 0.f);
#pragma unroll
        for (int j = 0; j < 32; j++) r[j] = sBb[j];
        const float4* v4 = reinterpret_cast<const float4*>(sWb);
        for (int k = 0; k < 32; k++) {
            float a = t[k];
#pragma unroll
            for (int q = 0; q < 8; q++) {
                float4 w = v4[k * 8 + q];
                r[4 * q + 0] += a * w.x;
                r[4 * q + 1] += a * w.y;
                r[4 * q + 2] += a * w.z;
                r[4 * q + 3] += a * w.w;
            }
        }
#pragma unroll
        for (int j = 0; j < 32; j++) r[j] = fmaxf(r[j], 0.f);
        float4* orow = reinterpret_cast<float4*>(out + (long long)node * 32);
#pragma unroll
        for (int q = 0; q < 8; q++) {
            float4 o;
            o.x = r[4 * q]; o.y = r[4 * q + 1]; o.z = r[4 * q + 2]; o.w = r[4 * q + 3];
            orow[q] = o;
        }
    } else {
#pragma unroll
        for (int j = 0; j < 32; j++) r[j] = 0.f;
    }

    int lane = tid & 63, wid = tid >> 6;
#pragma unroll
    for (int j = 0; j < 32; j++) {
        float v = r[j], v2 = v * v;
#pragma unroll
        for (int off = 32; off >= 1; off >>= 1) {
            v += __shfl_down(v, off, 64);
            v2 += __shfl_down(v2, off, 64);
        }
        if (lane == 0) { sSum[wid * 32 + j] = v; sSq[wid * 32 + j] = v2; }
    }
    __syncthreads();
    if (tid < 32) {
        float a = sSum[tid] + sSum[32 + tid] + sSum[64 + tid] + sSum[96 + tid];
        float b = sSq[tid] + sSq[32 + tid] + sSq[64 + tid] + sSq[96 + tid];
        atomicAdd(&stats[tid], a);
        atomicAdd(&stats[32 + tid], b);
    }
}

// ---------------- BN apply: out = (in - mu) * rsqrt(var+eps) * gamma + beta ----------------
__global__ __launch_bounds__(256) void bn_apply_k(const float* __restrict__ in,
                                                  float* __restrict__ out,
                                                  const float* __restrict__ stats,
                                                  const float* __restrict__ gamma,
                                                  const float* __restrict__ beta) {
    long long idx = (long long)blockIdx.x * 256 + threadIdx.x;
    if (idx < (long long)NN * 32) {
        int f = (int)(idx & 31);
        const float invn = 1.0f / NN;
        float mu = stats[f] * invn;
        float var = stats[32 + f] * invn - mu * mu;
        float sc = rsqrtf(var + BN_EPS) * gamma[f];
        out[idx] = (in[idx] - mu) * sc + beta[f];
    }
}

// ---------------- global add pool ----------------
__global__ __launch_bounds__(256) void pool_k(const float* __restrict__ h,
                                              const int* __restrict__ batch,
                                              float* __restrict__ pooled) {
    long long idx = (long long)blockIdx.x * 256 + threadIdx.x;
    if (idx < (long long)NN * 32) {
        int node = (int)(idx >> 5);
        int f = (int)(idx & 31);
        int g = batch[node];
        atomicAdd(&pooled[g * 32 + f], h[idx]);
    }
}

// ---------------- final FCs ----------------
__global__ __launch_bounds__(64) void final_k(const float* __restrict__ pooled,
                                              const float* __restrict__ w1,
                                              const float* __restrict__ b1,
                                              const float* __restrict__ w2,
                                              const float* __restrict__ b2,
                                              float* __restrict__ out) {
    int g = threadIdx.x;
    if (g >= NG) return;
    float t[32];
#pragma unroll
    for (int j = 0; j < 32; j++) t[j] = b1[j];
    for (int k = 0; k < 32; k++) {
        float a = pooled[g * 32 + k];
#pragma unroll
        for (int j = 0; j < 32; j++) t[j] += a * w1[k * 32 + j];
    }
#pragma unroll
    for (int j = 0; j < 32; j++) t[j] = fmaxf(t[j], 0.f);
    for (int c = 0; c < NC; c++) {
        float o = b2[c];
#pragma unroll
        for (int k = 0; k < 32; k++) o += t[k] * w2[k * NC + c];
        out[g * NC + c] = o;
    }
}

extern "C" void kernel_launch(void* const* d_in, const int* in_sizes, int n_in,
                              void* d_out, int out_size, void* d_ws, size_t ws_size,
                              hipStream_t stream) {
    const float* x = (const float*)d_in[0];
    const int* ei = (const int*)d_in[1];       // [2, NE]
    const int* batch = (const int*)d_in[2];    // [NN]
    const float* w1a = (const float*)d_in[3];
    const float* b1a = (const float*)d_in[4];
    const float* w1b = (const float*)d_in[5];
    const float* b1b = (const float*)d_in[6];
    const float* Wa = (const float*)d_in[7];   // [4,32,32]
    const float* Ba = (const float*)d_in[8];   // [4,32]
    const float* Wb = (const float*)d_in[9];
    const float* Bb = (const float*)d_in[10];
    const float* bn_gamma = (const float*)d_in[11]; // [5,32]
    const float* bn_beta = (const float*)d_in[12];
    const float* fc1w = (const float*)d_in[13];
    const float* fc1b = (const float*)d_in[14];
    const float* fc2w = (const float*)d_in[15];
    const float* fc2b = (const float*)d_in[16];
    float* out = (float*)d_out;

    float* ws = (float*)d_ws;
    float* agg = ws;                              // NN*64 floats (reused as NN*32 for layers 2-5)
    float* h = agg + (size_t)NN * 64;             // NN*32
    float* hb = h + (size_t)NN * 32;              // NN*32
    float* stats = hb + (size_t)NN * 32;          // 64
    float* pooled = stats + 64;                   // NG*32

    const int nodeBlocks = (NN + 255) / 256;
    const int elemBlocks = (NN * 32 + 255) / 256;

    // ---- layer 1 (64 feat) ----
    hipMemsetAsync(agg, 0, (size_t)NN * 64 * sizeof(float), stream);
    hipMemsetAsync(stats, 0, 64 * sizeof(float), stream);
    {
        long long tot = (long long)NE * 64;
        scatter_k<64><<<(int)((tot + 255) / 256), 256, 0, stream>>>(x, ei, agg);
    }
    mlp1_k<<<nodeBlocks, 256, 0, stream>>>(x, agg, w1a, b1a, w1b, b1b, hb, stats);
    bn_apply_k<<<elemBlocks, 256, 0, stream>>>(hb, h, stats, bn_gamma, bn_beta);

    // ---- layers 2-5 (32 feat) ----
    for (int i = 0; i < 4; i++) {
        hipMemsetAsync(agg, 0, (size_t)NN * 32 * sizeof(float), stream);
        hipMemsetAsync(stats, 0, 64 * sizeof(float), stream);
        {
            long long tot = (long long)NE * 32;
            scatter_k<32><<<(int)((tot + 255) / 256), 256, 0, stream>>>(h, ei, agg);
        }
        mlp32_k<<<nodeBlocks, 256, 0, stream>>>(h, agg, Wa + i * 1024, Ba + i * 32,
                                                Wb + i * 1024, Bb + i * 32, hb, stats);
        bn_apply_k<<<elemBlocks, 256, 0, stream>>>(hb, h, stats,
                                                   bn_gamma + (i + 1) * 32, bn_beta + (i + 1) * 32);
    }

    // ---- pool + FCs ----
    hipMemsetAsync(pooled, 0, (size_t)NG * 32 * sizeof(float), stream);
    pool_k<<<elemBlocks, 256, 0, stream>>>(h, batch, pooled);
    final_k<<<1, 64, 0, stream>>>(pooled, fc1w, fc1b, fc2w, fc2b, out);
}

// Round 2
// 983.860 us; speedup vs baseline: 1.6329x; 1.6329x over previous
//
#include <hip/hip_runtime.h>

#define NN 100000
#define NE 1600000
#define NF 64
#define DM 32
#define NG 64
#define NC 10
#define BN_EPS 1e-5f

#define NB_SCAN ((NN + 1023) / 1024)   // 98 scan blocks

// ================= CSR build =================
__global__ __launch_bounds__(256) void hist_k(const int* __restrict__ ei,
                                              int* __restrict__ counts) {
    int e = blockIdx.x * 256 + threadIdx.x;
    if (e < NE) atomicAdd(&counts[ei[NE + e]], 1);
}

// block-local exclusive scan (1024 elts/block), emits block sums
__global__ __launch_bounds__(1024) void scanA_k(const int* __restrict__ counts,
                                                int* __restrict__ excl,
                                                int* __restrict__ bsum) {
    __shared__ int s[1024];
    int t = threadIdx.x;
    int gi = blockIdx.x * 1024 + t;
    int v = (gi < NN) ? counts[gi] : 0;
    s[t] = v;
    __syncthreads();
    int acc = v;
    for (int off = 1; off < 1024; off <<= 1) {
        int add = (t >= off) ? s[t - off] : 0;
        __syncthreads();
        acc += add;
        s[t] = acc;
        __syncthreads();
    }
    if (gi < NN) excl[gi] = acc - v;          // exclusive within block
    if (t == 1023) bsum[blockIdx.x] = acc;    // block total
}

// exclusive scan of the (<=128) block sums, single block
__global__ __launch_bounds__(128) void scanB_k(int* __restrict__ bsum) {
    __shared__ int s[128];
    int t = threadIdx.x;
    int v = (t < NB_SCAN) ? bsum[t] : 0;
    s[t] = v;
    __syncthreads();
    int acc = v;
    for (int off = 1; off < 128; off <<= 1) {
        int add = (t >= off) ? s[t - off] : 0;
        __syncthreads();
        acc += add;
        s[t] = acc;
        __syncthreads();
    }
    if (t < NB_SCAN) bsum[t] = acc - v;       // exclusive
}

// add block offsets, init fill cursors, set rowptr[NN]
__global__ __launch_bounds__(1024) void scanC_k(int* __restrict__ rowptr,
                                                const int* __restrict__ bofs,
                                                int* __restrict__ rowcur) {
    int gi = blockIdx.x * 1024 + threadIdx.x;
    if (gi < NN) {
        int r = rowptr[gi] + bofs[blockIdx.x];
        rowptr[gi] = r;
        rowcur[gi] = r;
    }
    if (gi == NN) rowptr[NN] = NE;
}

__global__ __launch_bounds__(256) void fill_k(const int* __restrict__ ei,
                                              int* __restrict__ rowcur,
                                              int* __restrict__ csr) {
    int e = blockIdx.x * 256 + threadIdx.x;
    if (e < NE) {
        int d = ei[NE + e];
        int p = atomicAdd(&rowcur[d], 1);
        csr[p] = ei[e];
    }
}

// ================= gather: agg[n] = sum_{s in N(n)} x[s] =================
template <int F>
__global__ __launch_bounds__(256) void gather_k(const float* __restrict__ x,
                                                const int* __restrict__ rowptr,
                                                const int* __restrict__ csr,
                                                float* __restrict__ agg) {
    constexpr int LPN = F / 4;        // lanes per node (float4 each)
    constexpr int NPB = 256 / LPN;    // nodes per block
    int tid = threadIdx.x;
    int node = blockIdx.x * NPB + tid / LPN;
    int l = tid % LPN;
    if (node >= NN) return;
    int s = rowptr[node], e = rowptr[node + 1];
    const float4* x4 = reinterpret_cast<const float4*>(x);
    float4 acc = make_float4(0.f, 0.f, 0.f, 0.f);
    for (int i = s; i < e; i++) {
        int src = csr[i];
        float4 v = x4[(long long)src * LPN + l];
        acc.x += v.x; acc.y += v.y; acc.z += v.z; acc.w += v.w;
    }
    reinterpret_cast<float4*>(agg)[(long long)node * LPN + l] = acc;
}

// ---------------- layer 1 MLP: (x+agg)[64] -> relu -> [32] -> relu, + BN stats ----------------
__global__ __launch_bounds__(256) void mlp1_k(const float* __restrict__ x,
                                              const float* __restrict__ agg,
                                              const float* __restrict__ wa,
                                              const float* __restrict__ ba,
                                              const float* __restrict__ wb,
                                              const float* __restrict__ bb,
                                              float* __restrict__ out,
                                              float* __restrict__ stats) {
    __shared__ float sWa[64 * 32];
    __shared__ float sWb[32 * 32];
    __shared__ float sBa[32], sBb[32];
    __shared__ float sSum[4 * 32], sSq[4 * 32];
    int tid = threadIdx.x;
    for (int i = tid; i < 64 * 32; i += 256) sWa[i] = wa[i];
    for (int i = tid; i < 32 * 32; i += 256) sWb[i] = wb[i];
    if (tid < 32) { sBa[tid] = ba[tid]; sBb[tid] = bb[tid]; }
    __syncthreads();

    int node = blockIdx.x * 256 + tid;
    float r[32];
    if (node < NN) {
        float t[32];
#pragma unroll
        for (int j = 0; j < 32; j++) t[j] = sBa[j];
        const float4* xr = reinterpret_cast<const float4*>(x + (long long)node * 64);
        const float4* ar = reinterpret_cast<const float4*>(agg + (long long)node * 64);
        const float4* w4 = reinterpret_cast<const float4*>(sWa);
        for (int k4 = 0; k4 < 16; k4++) {
            float4 xv = xr[k4];
            float4 av = ar[k4];
            float a0 = xv.x + av.x, a1 = xv.y + av.y, a2 = xv.z + av.z, a3 = xv.w + av.w;
            int kb = k4 * 4;
#pragma unroll
            for (int q = 0; q < 8; q++) {
                float4 w0 = w4[(kb + 0) * 8 + q];
                float4 w1 = w4[(kb + 1) * 8 + q];
                float4 w2 = w4[(kb + 2) * 8 + q];
                float4 w3 = w4[(kb + 3) * 8 + q];
                t[4 * q + 0] += a0 * w0.x + a1 * w1.x + a2 * w2.x + a3 * w3.x;
                t[4 * q + 1] += a0 * w0.y + a1 * w1.y + a2 * w2.y + a3 * w3.y;
                t[4 * q + 2] += a0 * w0.z + a1 * w1.z + a2 * w2.z + a3 * w3.z;
                t[4 * q + 3] += a0 * w0.w + a1 * w1.w + a2 * w2.w + a3 * w3.w;
            }
        }
#pragma unroll
        for (int j = 0; j < 32; j++) t[j] = fmaxf(t[j], 0.f);
#pragma unroll
        for (int j = 0; j < 32; j++) r[j] = sBb[j];
        const float4* v4 = reinterpret_cast<const float4*>(sWb);
        for (int k = 0; k < 32; k++) {
            float a = t[k];
#pragma unroll
            for (int q = 0; q < 8; q++) {
                float4 w = v4[k * 8 + q];
                r[4 * q + 0] += a * w.x;
                r[4 * q + 1] += a * w.y;
                r[4 * q + 2] += a * w.z;
                r[4 * q + 3] += a * w.w;
            }
        }
#pragma unroll
        for (int j = 0; j < 32; j++) r[j] = fmaxf(r[j], 0.f);
        float4* orow = reinterpret_cast<float4*>(out + (long long)node * 32);
#pragma unroll
        for (int q = 0; q < 8; q++) {
            float4 o;
            o.x = r[4 * q]; o.y = r[4 * q + 1]; o.z = r[4 * q + 2]; o.w = r[4 * q + 3];
            orow[q] = o;
        }
    } else {
#pragma unroll
        for (int j = 0; j < 32; j++) r[j] = 0.f;
    }

    int lane = tid & 63, wid = tid >> 6;
#pragma unroll
    for (int j = 0; j < 32; j++) {
        float v = r[j], v2 = v * v;
#pragma unroll
        for (int off = 32; off >= 1; off >>= 1) {
            v += __shfl_down(v, off, 64);
            v2 += __shfl_down(v2, off, 64);
        }
        if (lane == 0) { sSum[wid * 32 + j] = v; sSq[wid * 32 + j] = v2; }
    }
    __syncthreads();
    if (tid < 32) {
        float a = sSum[tid] + sSum[32 + tid] + sSum[64 + tid] + sSum[96 + tid];
        float b = sSq[tid] + sSq[32 + tid] + sSq[64 + tid] + sSq[96 + tid];
        atomicAdd(&stats[tid], a);
        atomicAdd(&stats[32 + tid], b);
    }
}

// ---------------- layers 2-5 MLP: (h+agg)[32] -> relu -> [32] -> relu, + BN stats ----------------
__global__ __launch_bounds__(256) void mlp32_k(const float* __restrict__ hin,
                                               const float* __restrict__ agg,
                                               const float* __restrict__ wa,
                                               const float* __restrict__ ba,
                                               const float* __restrict__ wb,
                                               const float* __restrict__ bb,
                                               float* __restrict__ out,
                                               float* __restrict__ stats) {
    __shared__ float sWa[32 * 32];
    __shared__ float sWb[32 * 32];
    __shared__ float sBa[32], sBb[32];
    __shared__ float sSum[4 * 32], sSq[4 * 32];
    int tid = threadIdx.x;
    for (int i = tid; i < 32 * 32; i += 256) { sWa[i] = wa[i]; sWb[i] = wb[i]; }
    if (tid < 32) { sBa[tid] = ba[tid]; sBb[tid] = bb[tid]; }
    __syncthreads();

    int node = blockIdx.x * 256 + tid;
    float r[32];
    if (node < NN) {
        float t[32];
#pragma unroll
        for (int j = 0; j < 32; j++) t[j] = sBa[j];
        const float4* hr = reinterpret_cast<const float4*>(hin + (long long)node * 32);
        const float4* ar = reinterpret_cast<const float4*>(agg + (long long)node * 32);
        const float4* w4 = reinterpret_cast<const float4*>(sWa);
        for (int k4 = 0; k4 < 8; k4++) {
            float4 xv = hr[k4];
            float4 av = ar[k4];
            float a0 = xv.x + av.x, a1 = xv.y + av.y, a2 = xv.z + av.z, a3 = xv.w + av.w;
            int kb = k4 * 4;
#pragma unroll
            for (int q = 0; q < 8; q++) {
                float4 w0 = w4[(kb + 0) * 8 + q];
                float4 w1 = w4[(kb + 1) * 8 + q];
                float4 w2 = w4[(kb + 2) * 8 + q];
                float4 w3 = w4[(kb + 3) * 8 + q];
                t[4 * q + 0] += a0 * w0.x + a1 * w1.x + a2 * w2.x + a3 * w3.x;
                t[4 * q + 1] += a0 * w0.y + a1 * w1.y + a2 * w2.y + a3 * w3.y;
                t[4 * q + 2] += a0 * w0.z + a1 * w1.z + a2 * w2.z + a3 * w3.z;
                t[4 * q + 3] += a0 * w0.w + a1 * w1.w + a2 * w2.w + a3 * w3.w;
            }
        }
#pragma unroll
        for (int j = 0; j < 32; j++) t[j] = fmaxf(t[j], 0.f);
#pragma unroll
        for (int j = 0; j < 32; j++) r[j] = sBb[j];
        const float4* v4 = reinterpret_cast<const float4*>(sWb);
        for (int k = 0; k < 32; k++) {
            float a = t[k];
#pragma unroll
            for (int q = 0; q < 8; q++) {
                float4 w = v4[k * 8 + q];
                r[4 * q + 0] += a * w.x;
                r[4 * q + 1] += a * w.y;
                r[4 * q + 2] += a * w.z;
                r[4 * q + 3] += a * w.w;
            }
        }
#pragma unroll
        for (int j = 0; j < 32; j++) r[j] = fmaxf(r[j], 0.f);
        float4* orow = reinterpret_cast<float4*>(out + (long long)node * 32);
#pragma unroll
        for (int q = 0; q < 8; q++) {
            float4 o;
            o.x = r[4 * q]; o.y = r[4 * q + 1]; o.z = r[4 * q + 2]; o.w = r[4 * q + 3];
            orow[q] = o;
        }
    } else {
#pragma unroll
        for (int j = 0; j < 32; j++) r[j] = 0.f;
    }

    int lane = tid & 63, wid = tid >> 6;
#pragma unroll
    for (int j = 0; j < 32; j++) {
        float v = r[j], v2 = v * v;
#pragma unroll
        for (int off = 32; off >= 1; off >>= 1) {
            v += __shfl_down(v, off, 64);
            v2 += __shfl_down(v2, off, 64);
        }
        if (lane == 0) { sSum[wid * 32 + j] = v; sSq[wid * 32 + j] = v2; }
    }
    __syncthreads();
    if (tid < 32) {
        float a = sSum[tid] + sSum[32 + tid] + sSum[64 + tid] + sSum[96 + tid];
        float b = sSq[tid] + sSq[32 + tid] + sSq[64 + tid] + sSq[96 + tid];
        atomicAdd(&stats[tid], a);
        atomicAdd(&stats[32 + tid], b);
    }
}

// ---------------- BN apply ----------------
__global__ __launch_bounds__(256) void bn_apply_k(const float* __restrict__ in,
                                                  float* __restrict__ out,
                                                  const float* __restrict__ stats,
                                                  const float* __restrict__ gamma,
                                                  const float* __restrict__ beta) {
    long long idx = (long long)blockIdx.x * 256 + threadIdx.x;
    if (idx < (long long)NN * 32) {
        int f = (int)(idx & 31);
        const float invn = 1.0f / NN;
        float mu = stats[f] * invn;
        float var = stats[32 + f] * invn - mu * mu;
        float sc = rsqrtf(var + BN_EPS) * gamma[f];
        out[idx] = (in[idx] - mu) * sc + beta[f];
    }
}

// ---------------- global add pool ----------------
__global__ __launch_bounds__(256) void pool_k(const float* __restrict__ h,
                                              const int* __restrict__ batch,
                                              float* __restrict__ pooled) {
    long long idx = (long long)blockIdx.x * 256 + threadIdx.x;
    if (idx < (long long)NN * 32) {
        int node = (int)(idx >> 5);
        int f = (int)(idx & 31);
        int g = batch[node];
        atomicAdd(&pooled[g * 32 + f], h[idx]);
    }
}

// ---------------- final FCs ----------------
__global__ __launch_bounds__(64) void final_k(const float* __restrict__ pooled,
                                              const float* __restrict__ w1,
                                              const float* __restrict__ b1,
                                              const float* __restrict__ w2,
                                              const float* __restrict__ b2,
                                              float* __restrict__ out) {
    int g = threadIdx.x;
    if (g >= NG) return;
    float t[32];
#pragma unroll
    for (int j = 0; j < 32; j++) t[j] = b1[j];
    for (int k = 0; k < 32; k++) {
        float a = pooled[g * 32 + k];
#pragma unroll
        for (int j = 0; j < 32; j++) t[j] += a * w1[k * 32 + j];
    }
#pragma unroll
    for (int j = 0; j < 32; j++) t[j] = fmaxf(t[j], 0.f);
    for (int c = 0; c < NC; c++) {
        float o = b2[c];
#pragma unroll
        for (int k = 0; k < 32; k++) o += t[k] * w2[k * NC + c];
        out[g * NC + c] = o;
    }
}

extern "C" void kernel_launch(void* const* d_in, const int* in_sizes, int n_in,
                              void* d_out, int out_size, void* d_ws, size_t ws_size,
                              hipStream_t stream) {
    const float* x = (const float*)d_in[0];
    const int* ei = (const int*)d_in[1];
    const int* batch = (const int*)d_in[2];
    const float* w1a = (const float*)d_in[3];
    const float* b1a = (const float*)d_in[4];
    const float* w1b = (const float*)d_in[5];
    const float* b1b = (const float*)d_in[6];
    const float* Wa = (const float*)d_in[7];
    const float* Ba = (const float*)d_in[8];
    const float* Wb = (const float*)d_in[9];
    const float* Bb = (const float*)d_in[10];
    const float* bn_gamma = (const float*)d_in[11];
    const float* bn_beta = (const float*)d_in[12];
    const float* fc1w = (const float*)d_in[13];
    const float* fc1b = (const float*)d_in[14];
    const float* fc2w = (const float*)d_in[15];
    const float* fc2b = (const float*)d_in[16];
    float* out = (float*)d_out;

    float* ws = (float*)d_ws;
    float* agg = ws;                               // NN*64 floats
    float* h = agg + (size_t)NN * 64;              // NN*32
    float* hb = h + (size_t)NN * 32;               // NN*32
    float* stats = hb + (size_t)NN * 32;           // 64
    float* pooled = stats + 64;                    // NG*32
    int* rowptr = (int*)(pooled + NG * 32);        // NN+1
    int* rowcur = rowptr + NN + 1;                 // NN
    int* bsum = rowcur + NN;                       // 128
    int* csr = bsum + 128;                         // NE

    const int nodeBlocks = (NN + 255) / 256;
    const int elemBlocks = (NN * 32 + 255) / 256;
    const int edgeBlocks = (NE + 255) / 256;

    // ---- CSR build (in-graph, every call) ----
    hipMemsetAsync(rowcur, 0, (size_t)NN * sizeof(int), stream);
    hist_k<<<edgeBlocks, 256, 0, stream>>>(ei, rowcur);
    scanA_k<<<NB_SCAN, 1024, 0, stream>>>(rowcur, rowptr, bsum);
    scanB_k<<<1, 128, 0, stream>>>(bsum);
    scanC_k<<<NB_SCAN, 1024, 0, stream>>>(rowptr, bsum, rowcur);
    fill_k<<<edgeBlocks, 256, 0, stream>>>(ei, rowcur, csr);

    // ---- layer 1 (64 feat) ----
    hipMemsetAsync(stats, 0, 64 * sizeof(float), stream);
    gather_k<64><<<NN / 16, 256, 0, stream>>>(x, rowptr, csr, agg);
    mlp1_k<<<nodeBlocks, 256, 0, stream>>>(x, agg, w1a, b1a, w1b, b1b, hb, stats);
    bn_apply_k<<<elemBlocks, 256, 0, stream>>>(hb, h, stats, bn_gamma, bn_beta);

    // ---- layers 2-5 (32 feat) ----
    for (int i = 0; i < 4; i++) {
        hipMemsetAsync(stats, 0, 64 * sizeof(float), stream);
        gather_k<32><<<NN / 32, 256, 0, stream>>>(h, rowptr, csr, agg);
        mlp32_k<<<nodeBlocks, 256, 0, stream>>>(h, agg, Wa + i * 1024, Ba + i * 32,
                                                Wb + i * 1024, Bb + i * 32, hb, stats);
        bn_apply_k<<<elemBlocks, 256, 0, stream>>>(hb, h, stats,
                                                   bn_gamma + (i + 1) * 32, bn_beta + (i + 1) * 32);
    }

    // ---- pool + FCs ----
    hipMemsetAsync(pooled, 0, (size_t)NG * 32 * sizeof(float), stream);
    pool_k<<<elemBlocks, 256, 0, stream>>>(h, batch, pooled);
    final_k<<<1, 64, 0, stream>>>(pooled, fc1w, fc1b, fc2w, fc2b, out);
}

// Round 3
// 786.349 us; speedup vs baseline: 2.0430x; 1.2512x over previous
//
#include <hip/hip_runtime.h>

#define NN 100000
#define NE 1600000
#define NF 64
#define DM 32
#define NG 64
#define NC 10
#define BN_EPS 1e-5f

#define NB_SCAN ((NN + 1023) / 1024)   // 98 scan blocks

// ================= CSR build =================
__global__ __launch_bounds__(256) void hist_k(const int* __restrict__ ei,
                                              int* __restrict__ counts) {
    int e = blockIdx.x * 256 + threadIdx.x;
    if (e < NE) atomicAdd(&counts[ei[NE + e]], 1);
}

// block-local exclusive scan (1024 elts/block), emits block sums
__global__ __launch_bounds__(1024) void scanA_k(const int* __restrict__ counts,
                                                int* __restrict__ excl,
                                                int* __restrict__ bsum) {
    __shared__ int s[1024];
    int t = threadIdx.x;
    int gi = blockIdx.x * 1024 + t;
    int v = (gi < NN) ? counts[gi] : 0;
    s[t] = v;
    __syncthreads();
    int acc = v;
    for (int off = 1; off < 1024; off <<= 1) {
        int add = (t >= off) ? s[t - off] : 0;
        __syncthreads();
        acc += add;
        s[t] = acc;
        __syncthreads();
    }
    if (gi < NN) excl[gi] = acc - v;
    if (t == 1023) bsum[blockIdx.x] = acc;
}

__global__ __launch_bounds__(128) void scanB_k(int* __restrict__ bsum) {
    __shared__ int s[128];
    int t = threadIdx.x;
    int v = (t < NB_SCAN) ? bsum[t] : 0;
    s[t] = v;
    __syncthreads();
    int acc = v;
    for (int off = 1; off < 128; off <<= 1) {
        int add = (t >= off) ? s[t - off] : 0;
        __syncthreads();
        acc += add;
        s[t] = acc;
        __syncthreads();
    }
    if (t < NB_SCAN) bsum[t] = acc - v;
}

__global__ __launch_bounds__(1024) void scanC_k(int* __restrict__ rowptr,
                                                const int* __restrict__ bofs,
                                                int* __restrict__ rowcur) {
    int gi = blockIdx.x * 1024 + threadIdx.x;
    if (gi < NN) {
        int r = rowptr[gi] + bofs[blockIdx.x];
        rowptr[gi] = r;
        rowcur[gi] = r;
    }
    if (gi == NN) rowptr[NN] = NE;
}

__global__ __launch_bounds__(256) void fill_k(const int* __restrict__ ei,
                                              int* __restrict__ rowcur,
                                              int* __restrict__ csr) {
    int e = blockIdx.x * 256 + threadIdx.x;
    if (e < NE) {
        int d = ei[NE + e];
        int p = atomicAdd(&rowcur[d], 1);
        csr[p] = ei[e];
    }
}

// ================= gather: agg[n] = sum_{s in N(n)} x[s] =================
template <int F>
__global__ __launch_bounds__(256) void gather_k(const float* __restrict__ x,
                                                const int* __restrict__ rowptr,
                                                const int* __restrict__ csr,
                                                float* __restrict__ agg) {
    constexpr int LPN = F / 4;
    constexpr int NPB = 256 / LPN;
    int tid = threadIdx.x;
    int node = blockIdx.x * NPB + tid / LPN;
    int l = tid % LPN;
    if (node >= NN) return;
    int s = rowptr[node], e = rowptr[node + 1];
    const float4* x4 = reinterpret_cast<const float4*>(x);
    float4 acc = make_float4(0.f, 0.f, 0.f, 0.f);
    for (int i = s; i < e; i++) {
        int src = csr[i];
        float4 v = x4[(long long)src * LPN + l];
        acc.x += v.x; acc.y += v.y; acc.z += v.z; acc.w += v.w;
    }
    reinterpret_cast<float4*>(agg)[(long long)node * LPN + l] = acc;
}

// ---------------- layer 1 MLP ----------------
__global__ __launch_bounds__(256) void mlp1_k(const float* __restrict__ x,
                                              const float* __restrict__ agg,
                                              const float* __restrict__ wa,
                                              const float* __restrict__ ba,
                                              const float* __restrict__ wb,
                                              const float* __restrict__ bb,
                                              float* __restrict__ out,
                                              float* __restrict__ stats) {
    __shared__ float sWa[64 * 32];
    __shared__ float sWb[32 * 32];
    __shared__ float sBa[32], sBb[32];
    __shared__ float sSum[4 * 32], sSq[4 * 32];
    int tid = threadIdx.x;
    for (int i = tid; i < 64 * 32; i += 256) sWa[i] = wa[i];
    for (int i = tid; i < 32 * 32; i += 256) sWb[i] = wb[i];
    if (tid < 32) { sBa[tid] = ba[tid]; sBb[tid] = bb[tid]; }
    __syncthreads();

    int node = blockIdx.x * 256 + tid;
    float r[32];
    if (node < NN) {
        float t[32];
#pragma unroll
        for (int j = 0; j < 32; j++) t[j] = sBa[j];
        const float4* xr = reinterpret_cast<const float4*>(x + (long long)node * 64);
        const float4* ar = reinterpret_cast<const float4*>(agg + (long long)node * 64);
        const float4* w4 = reinterpret_cast<const float4*>(sWa);
        for (int k4 = 0; k4 < 16; k4++) {
            float4 xv = xr[k4];
            float4 av = ar[k4];
            float a0 = xv.x + av.x, a1 = xv.y + av.y, a2 = xv.z + av.z, a3 = xv.w + av.w;
            int kb = k4 * 4;
#pragma unroll
            for (int q = 0; q < 8; q++) {
                float4 w0 = w4[(kb + 0) * 8 + q];
                float4 w1 = w4[(kb + 1) * 8 + q];
                float4 w2 = w4[(kb + 2) * 8 + q];
                float4 w3 = w4[(kb + 3) * 8 + q];
                t[4 * q + 0] += a0 * w0.x + a1 * w1.x + a2 * w2.x + a3 * w3.x;
                t[4 * q + 1] += a0 * w0.y + a1 * w1.y + a2 * w2.y + a3 * w3.y;
                t[4 * q + 2] += a0 * w0.z + a1 * w1.z + a2 * w2.z + a3 * w3.z;
                t[4 * q + 3] += a0 * w0.w + a1 * w1.w + a2 * w2.w + a3 * w3.w;
            }
        }
#pragma unroll
        for (int j = 0; j < 32; j++) t[j] = fmaxf(t[j], 0.f);
#pragma unroll
        for (int j = 0; j < 32; j++) r[j] = sBb[j];
        const float4* v4 = reinterpret_cast<const float4*>(sWb);
        for (int k = 0; k < 32; k++) {
            float a = t[k];
#pragma unroll
            for (int q = 0; q < 8; q++) {
                float4 w = v4[k * 8 + q];
                r[4 * q + 0] += a * w.x;
                r[4 * q + 1] += a * w.y;
                r[4 * q + 2] += a * w.z;
                r[4 * q + 3] += a * w.w;
            }
        }
#pragma unroll
        for (int j = 0; j < 32; j++) r[j] = fmaxf(r[j], 0.f);
        float4* orow = reinterpret_cast<float4*>(out + (long long)node * 32);
#pragma unroll
        for (int q = 0; q < 8; q++) {
            float4 o;
            o.x = r[4 * q]; o.y = r[4 * q + 1]; o.z = r[4 * q + 2]; o.w = r[4 * q + 3];
            orow[q] = o;
        }
    } else {
#pragma unroll
        for (int j = 0; j < 32; j++) r[j] = 0.f;
    }

    int lane = tid & 63, wid = tid >> 6;
#pragma unroll
    for (int j = 0; j < 32; j++) {
        float v = r[j], v2 = v * v;
#pragma unroll
        for (int off = 32; off >= 1; off >>= 1) {
            v += __shfl_down(v, off, 64);
            v2 += __shfl_down(v2, off, 64);
        }
        if (lane == 0) { sSum[wid * 32 + j] = v; sSq[wid * 32 + j] = v2; }
    }
    __syncthreads();
    if (tid < 32) {
        float a = sSum[tid] + sSum[32 + tid] + sSum[64 + tid] + sSum[96 + tid];
        float b = sSq[tid] + sSq[32 + tid] + sSq[64 + tid] + sSq[96 + tid];
        atomicAdd(&stats[tid], a);
        atomicAdd(&stats[32 + tid], b);
    }
}

// ---------------- layers 2-5 MLP ----------------
__global__ __launch_bounds__(256) void mlp32_k(const float* __restrict__ hin,
                                               const float* __restrict__ agg,
                                               const float* __restrict__ wa,
                                               const float* __restrict__ ba,
                                               const float* __restrict__ wb,
                                               const float* __restrict__ bb,
                                               float* __restrict__ out,
                                               float* __restrict__ stats) {
    __shared__ float sWa[32 * 32];
    __shared__ float sWb[32 * 32];
    __shared__ float sBa[32], sBb[32];
    __shared__ float sSum[4 * 32], sSq[4 * 32];
    int tid = threadIdx.x;
    for (int i = tid; i < 32 * 32; i += 256) { sWa[i] = wa[i]; sWb[i] = wb[i]; }
    if (tid < 32) { sBa[tid] = ba[tid]; sBb[tid] = bb[tid]; }
    __syncthreads();

    int node = blockIdx.x * 256 + tid;
    float r[32];
    if (node < NN) {
        float t[32];
#pragma unroll
        for (int j = 0; j < 32; j++) t[j] = sBa[j];
        const float4* hr = reinterpret_cast<const float4*>(hin + (long long)node * 32);
        const float4* ar = reinterpret_cast<const float4*>(agg + (long long)node * 32);
        const float4* w4 = reinterpret_cast<const float4*>(sWa);
        for (int k4 = 0; k4 < 8; k4++) {
            float4 xv = hr[k4];
            float4 av = ar[k4];
            float a0 = xv.x + av.x, a1 = xv.y + av.y, a2 = xv.z + av.z, a3 = xv.w + av.w;
            int kb = k4 * 4;
#pragma unroll
            for (int q = 0; q < 8; q++) {
                float4 w0 = w4[(kb + 0) * 8 + q];
                float4 w1 = w4[(kb + 1) * 8 + q];
                float4 w2 = w4[(kb + 2) * 8 + q];
                float4 w3 = w4[(kb + 3) * 8 + q];
                t[4 * q + 0] += a0 * w0.x + a1 * w1.x + a2 * w2.x + a3 * w3.x;
                t[4 * q + 1] += a0 * w0.y + a1 * w1.y + a2 * w2.y + a3 * w3.y;
                t[4 * q + 2] += a0 * w0.z + a1 * w1.z + a2 * w2.z + a3 * w3.z;
                t[4 * q + 3] += a0 * w0.w + a1 * w1.w + a2 * w2.w + a3 * w3.w;
            }
        }
#pragma unroll
        for (int j = 0; j < 32; j++) t[j] = fmaxf(t[j], 0.f);
#pragma unroll
        for (int j = 0; j < 32; j++) r[j] = sBb[j];
        const float4* v4 = reinterpret_cast<const float4*>(sWb);
        for (int k = 0; k < 32; k++) {
            float a = t[k];
#pragma unroll
            for (int q = 0; q < 8; q++) {
                float4 w = v4[k * 8 + q];
                r[4 * q + 0] += a * w.x;
                r[4 * q + 1] += a * w.y;
                r[4 * q + 2] += a * w.z;
                r[4 * q + 3] += a * w.w;
            }
        }
#pragma unroll
        for (int j = 0; j < 32; j++) r[j] = fmaxf(r[j], 0.f);
        float4* orow = reinterpret_cast<float4*>(out + (long long)node * 32);
#pragma unroll
        for (int q = 0; q < 8; q++) {
            float4 o;
            o.x = r[4 * q]; o.y = r[4 * q + 1]; o.z = r[4 * q + 2]; o.w = r[4 * q + 3];
            orow[q] = o;
        }
    } else {
#pragma unroll
        for (int j = 0; j < 32; j++) r[j] = 0.f;
    }

    int lane = tid & 63, wid = tid >> 6;
#pragma unroll
    for (int j = 0; j < 32; j++) {
        float v = r[j], v2 = v * v;
#pragma unroll
        for (int off = 32; off >= 1; off >>= 1) {
            v += __shfl_down(v, off, 64);
            v2 += __shfl_down(v2, off, 64);
        }
        if (lane == 0) { sSum[wid * 32 + j] = v; sSq[wid * 32 + j] = v2; }
    }
    __syncthreads();
    if (tid < 32) {
        float a = sSum[tid] + sSum[32 + tid] + sSum[64 + tid] + sSum[96 + tid];
        float b = sSq[tid] + sSq[32 + tid] + sSq[64 + tid] + sSq[96 + tid];
        atomicAdd(&stats[tid], a);
        atomicAdd(&stats[32 + tid], b);
    }
}

// ---------------- BN apply ----------------
__global__ __launch_bounds__(256) void bn_apply_k(const float* __restrict__ in,
                                                  float* __restrict__ out,
                                                  const float* __restrict__ stats,
                                                  const float* __restrict__ gamma,
                                                  const float* __restrict__ beta) {
    long long idx = (long long)blockIdx.x * 256 + threadIdx.x;
    if (idx < (long long)NN * 32) {
        int f = (int)(idx & 31);
        const float invn = 1.0f / NN;
        float mu = stats[f] * invn;
        float var = stats[32 + f] * invn - mu * mu;
        float sc = rsqrtf(var + BN_EPS) * gamma[f];
        out[idx] = (in[idx] - mu) * sc + beta[f];
    }
}

// ---------------- global add pool: privatized, exploits sorted batch ----------------
// block covers 512 nodes; thread (p,f) walks 64 consecutive nodes' feature f,
// flushing one atomic per graph-id change (~1-2 per thread).
#define POOL_NPB 512
__global__ __launch_bounds__(256) void pool2_k(const float* __restrict__ h,
                                               const int* __restrict__ batch,
                                               float* __restrict__ pooled) {
    int tid = threadIdx.x;
    int f = tid & 31;
    int p = tid >> 5;                       // 8 parts
    int n0 = blockIdx.x * POOL_NPB + p * (POOL_NPB / 8);
    int n1 = n0 + POOL_NPB / 8;
    if (n1 > NN) n1 = NN;
    if (n0 >= NN) return;
    float acc = 0.f;
    int cur = batch[n0];
    for (int n = n0; n < n1; n++) {
        int g = batch[n];
        if (g != cur) {
            atomicAdd(&pooled[cur * 32 + f], acc);
            cur = g;
            acc = 0.f;
        }
        acc += h[(long long)n * 32 + f];
    }
    atomicAdd(&pooled[cur * 32 + f], acc);
}

// ---------------- final FCs ----------------
__global__ __launch_bounds__(64) void final_k(const float* __restrict__ pooled,
                                              const float* __restrict__ w1,
                                              const float* __restrict__ b1,
                                              const float* __restrict__ w2,
                                              const float* __restrict__ b2,
                                              float* __restrict__ out) {
    int g = threadIdx.x;
    if (g >= NG) return;
    float t[32];
#pragma unroll
    for (int j = 0; j < 32; j++) t[j] = b1[j];
    for (int k = 0; k < 32; k++) {
        float a = pooled[g * 32 + k];
#pragma unroll
        for (int j = 0; j < 32; j++) t[j] += a * w1[k * 32 + j];
    }
#pragma unroll
    for (int j = 0; j < 32; j++) t[j] = fmaxf(t[j], 0.f);
    for (int c = 0; c < NC; c++) {
        float o = b2[c];
#pragma unroll
        for (int k = 0; k < 32; k++) o += t[k] * w2[k * NC + c];
        out[g * NC + c] = o;
    }
}

extern "C" void kernel_launch(void* const* d_in, const int* in_sizes, int n_in,
                              void* d_out, int out_size, void* d_ws, size_t ws_size,
                              hipStream_t stream) {
    const float* x = (const float*)d_in[0];
    const int* ei = (const int*)d_in[1];
    const int* batch = (const int*)d_in[2];
    const float* w1a = (const float*)d_in[3];
    const float* b1a = (const float*)d_in[4];
    const float* w1b = (const float*)d_in[5];
    const float* b1b = (const float*)d_in[6];
    const float* Wa = (const float*)d_in[7];
    const float* Ba = (const float*)d_in[8];
    const float* Wb = (const float*)d_in[9];
    const float* Bb = (const float*)d_in[10];
    const float* bn_gamma = (const float*)d_in[11];
    const float* bn_beta = (const float*)d_in[12];
    const float* fc1w = (const float*)d_in[13];
    const float* fc1b = (const float*)d_in[14];
    const float* fc2w = (const float*)d_in[15];
    const float* fc2b = (const float*)d_in[16];
    float* out = (float*)d_out;

    float* ws = (float*)d_ws;
    float* agg = ws;                               // NN*64 floats
    float* h = agg + (size_t)NN * 64;              // NN*32
    float* hb = h + (size_t)NN * 32;               // NN*32
    float* stats = hb + (size_t)NN * 32;           // 64
    float* pooled = stats + 64;                    // NG*32
    int* rowptr = (int*)(pooled + NG * 32);        // NN+1
    int* rowcur = rowptr + NN + 1;                 // NN
    int* bsum = rowcur + NN;                       // 128
    int* csr = bsum + 128;                         // NE

    const int nodeBlocks = (NN + 255) / 256;
    const int elemBlocks = (NN * 32 + 255) / 256;
    const int edgeBlocks = (NE + 255) / 256;

    // ---- CSR build ----
    hipMemsetAsync(rowcur, 0, (size_t)NN * sizeof(int), stream);
    hist_k<<<edgeBlocks, 256, 0, stream>>>(ei, rowcur);
    scanA_k<<<NB_SCAN, 1024, 0, stream>>>(rowcur, rowptr, bsum);
    scanB_k<<<1, 128, 0, stream>>>(bsum);
    scanC_k<<<NB_SCAN, 1024, 0, stream>>>(rowptr, bsum, rowcur);
    fill_k<<<edgeBlocks, 256, 0, stream>>>(ei, rowcur, csr);

    // ---- layer 1 (64 feat) ----
    hipMemsetAsync(stats, 0, 64 * sizeof(float), stream);
    gather_k<64><<<NN / 16, 256, 0, stream>>>(x, rowptr, csr, agg);
    mlp1_k<<<nodeBlocks, 256, 0, stream>>>(x, agg, w1a, b1a, w1b, b1b, hb, stats);
    bn_apply_k<<<elemBlocks, 256, 0, stream>>>(hb, h, stats, bn_gamma, bn_beta);

    // ---- layers 2-5 (32 feat) ----
    for (int i = 0; i < 4; i++) {
        hipMemsetAsync(stats, 0, 64 * sizeof(float), stream);
        gather_k<32><<<NN / 32, 256, 0, stream>>>(h, rowptr, csr, agg);
        mlp32_k<<<nodeBlocks, 256, 0, stream>>>(h, agg, Wa + i * 1024, Ba + i * 32,
                                                Wb + i * 1024, Bb + i * 32, hb, stats);
        bn_apply_k<<<elemBlocks, 256, 0, stream>>>(hb, h, stats,
                                                   bn_gamma + (i + 1) * 32, bn_beta + (i + 1) * 32);
    }

    // ---- pool + FCs ----
    hipMemsetAsync(pooled, 0, (size_t)NG * 32 * sizeof(float), stream);
    pool2_k<<<(NN + POOL_NPB - 1) / POOL_NPB, 256, 0, stream>>>(h, batch, pooled);
    final_k<<<1, 64, 0, stream>>>(pooled, fc1w, fc1b, fc2w, fc2b, out);
}

// Round 4
// 589.384 us; speedup vs baseline: 2.7258x; 1.3342x over previous
//
#include <hip/hip_runtime.h>

#define NN 100000
#define NE 1600000
#define NF 64
#define DM 32
#define NG 64
#define NC 10
#define BN_EPS 1e-5f

#define BSHIFT 8
#define NBUCK ((NN + 255) >> 8)        // 391 buckets of 256 nodes
#define CHUNK 8192                     // edges per binning block
#define NCH ((NE + CHUNK - 1) / CHUNK) // 196

// ============ CSR build via bucket counting-sort ============
// A: per-bucket edge counts (LDS-privatized histogram)
__global__ __launch_bounds__(256) void binA_k(const int* __restrict__ ei,
                                              int* __restrict__ bcnt) {
    __shared__ int h[NBUCK];
    for (int i = threadIdx.x; i < NBUCK; i += 256) h[i] = 0;
    __syncthreads();
    long long base = (long long)blockIdx.x * CHUNK;
    int n = (int)((NE - base < CHUNK) ? (NE - base) : CHUNK);
    for (int i = threadIdx.x; i < n; i += 256) {
        int d = ei[NE + base + i];
        atomicAdd(&h[d >> BSHIFT], 1);
    }
    __syncthreads();
    for (int i = threadIdx.x; i < NBUCK; i += 256)
        if (h[i]) atomicAdd(&bcnt[i], h[i]);
}

// B: exclusive scan of bucket counts -> bucket bases + cursors
__global__ __launch_bounds__(512) void binB_k(const int* __restrict__ bcnt,
                                              int* __restrict__ bbase,
                                              int* __restrict__ bcur) {
    __shared__ int s[512];
    int t = threadIdx.x;
    int v = (t < NBUCK) ? bcnt[t] : 0;
    s[t] = v;
    __syncthreads();
    int acc = v;
    for (int off = 1; off < 512; off <<= 1) {
        int add = (t >= off) ? s[t - off] : 0;
        __syncthreads();
        acc += add;
        s[t] = acc;
        __syncthreads();
    }
    if (t < NBUCK) { bbase[t] = acc - v; bcur[t] = acc - v; }
    if (t == 0) bbase[NBUCK] = NE;
}

// C: scatter edges into bucket-grouped array (contiguous per-bucket chunks)
__global__ __launch_bounds__(256) void binC_k(const int* __restrict__ ei,
                                              int* __restrict__ bcur,
                                              int2* __restrict__ binned) {
    __shared__ int cnt[NBUCK];
    __shared__ int ofs[NBUCK];
    __shared__ int idx[NBUCK];
    for (int i = threadIdx.x; i < NBUCK; i += 256) { cnt[i] = 0; idx[i] = 0; }
    __syncthreads();
    long long base = (long long)blockIdx.x * CHUNK;
    int n = (int)((NE - base < CHUNK) ? (NE - base) : CHUNK);
    int d[CHUNK / 256];
#pragma unroll
    for (int k = 0; k < CHUNK / 256; k++) {
        int i = threadIdx.x + k * 256;
        int dd = (i < n) ? ei[NE + base + i] : -1;
        d[k] = dd;
        if (dd >= 0) atomicAdd(&cnt[dd >> BSHIFT], 1);
    }
    __syncthreads();
    for (int i = threadIdx.x; i < NBUCK; i += 256)
        if (cnt[i]) ofs[i] = atomicAdd(&bcur[i], cnt[i]);
    __syncthreads();
#pragma unroll
    for (int k = 0; k < CHUNK / 256; k++) {
        int i = threadIdx.x + k * 256;
        if (i < n) {
            int src = ei[base + i];
            int b = d[k] >> BSHIFT;
            int l = atomicAdd(&idx[b], 1);
            binned[ofs[b] + l] = make_int2(src, d[k]);
        }
    }
}

// D: one block per bucket -> rowptr (LDS count + scan) + csr placement
__global__ __launch_bounds__(256) void binD_k(const int2* __restrict__ binned,
                                              const int* __restrict__ bbase,
                                              int* __restrict__ rowptr,
                                              int* __restrict__ csr) {
    __shared__ int cnt[256];
    __shared__ int cur[256];
    __shared__ int s[256];
    int b = blockIdx.x;
    int n0 = b << BSHIFT;
    int e0 = bbase[b], e1 = bbase[b + 1];
    int t = threadIdx.x;
    cnt[t] = 0;
    __syncthreads();
    for (int e = e0 + t; e < e1; e += 256) atomicAdd(&cnt[binned[e].y - n0], 1);
    __syncthreads();
    int v = cnt[t];
    s[t] = v;
    __syncthreads();
    int acc = v;
    for (int off = 1; off < 256; off <<= 1) {
        int add = (t >= off) ? s[t - off] : 0;
        __syncthreads();
        acc += add;
        s[t] = acc;
        __syncthreads();
    }
    int base = e0 + acc - v;
    int node = n0 + t;
    if (node < NN) rowptr[node] = base;
    cur[t] = base;
    if (b == NBUCK - 1 && t == 0) rowptr[NN] = NE;
    __syncthreads();
    for (int e = e0 + t; e < e1; e += 256) {
        int2 ed = binned[e];
        int p = atomicAdd(&cur[ed.y - n0], 1);
        csr[p] = ed.x;
    }
}

// ============ gather (layer 1, plain, F=64) ============
__global__ __launch_bounds__(256) void gather64_k(const float* __restrict__ x,
                                                  const int* __restrict__ rowptr,
                                                  const int* __restrict__ csr,
                                                  float* __restrict__ agg) {
    int tid = threadIdx.x;
    int node = blockIdx.x * 16 + tid / 16;
    int l = tid % 16;
    if (node >= NN) return;
    int s = rowptr[node], e = rowptr[node + 1];
    const float4* x4 = reinterpret_cast<const float4*>(x);
    float4 acc = make_float4(0.f, 0.f, 0.f, 0.f);
    for (int i = s; i < e; i++) {
        int src = csr[i];
        float4 v = x4[(long long)src * 16 + l];
        acc.x += v.x; acc.y += v.y; acc.z += v.z; acc.w += v.w;
    }
    reinterpret_cast<float4*>(agg)[(long long)node * 16 + l] = acc;
}

// ============ gather with fused BN of previous layer (F=32) ============
// agg[n] = sum_j BN(h[j]) = sc * (sum_j h[j]) + deg * sh
__global__ __launch_bounds__(256) void gather_bn_k(const float* __restrict__ h,
                                                   const int* __restrict__ rowptr,
                                                   const int* __restrict__ csr,
                                                   float* __restrict__ agg,
                                                   const float* __restrict__ st,
                                                   const float* __restrict__ gamma,
                                                   const float* __restrict__ beta) {
    int tid = threadIdx.x;
    int node = blockIdx.x * 32 + tid / 8;
    int l = tid % 8;
    if (node >= NN) return;
    const float invn = 1.0f / NN;
    float sc[4], sh[4];
#pragma unroll
    for (int c = 0; c < 4; c++) {
        int f = 4 * l + c;
        float mu = st[f] * invn;
        float var = st[32 + f] * invn - mu * mu;
        float scale = rsqrtf(var + BN_EPS) * gamma[f];
        sc[c] = scale;
        sh[c] = beta[f] - mu * scale;
    }
    int s = rowptr[node], e = rowptr[node + 1];
    const float4* h4 = reinterpret_cast<const float4*>(h);
    float4 acc = make_float4(0.f, 0.f, 0.f, 0.f);
    for (int i = s; i < e; i++) {
        int src = csr[i];
        float4 v = h4[(long long)src * 8 + l];
        acc.x += v.x; acc.y += v.y; acc.z += v.z; acc.w += v.w;
    }
    float deg = (float)(e - s);
    acc.x = acc.x * sc[0] + deg * sh[0];
    acc.y = acc.y * sc[1] + deg * sh[1];
    acc.z = acc.z * sc[2] + deg * sh[2];
    acc.w = acc.w * sc[3] + deg * sh[3];
    reinterpret_cast<float4*>(agg)[(long long)node * 8 + l] = acc;
}

// ============ layer 1 MLP: (x+agg)[64] -> relu -> [32] -> relu, + BN stats ============
__global__ __launch_bounds__(256) void mlp1_k(const float* __restrict__ x,
                                              const float* __restrict__ agg,
                                              const float* __restrict__ wa,
                                              const float* __restrict__ ba,
                                              const float* __restrict__ wb,
                                              const float* __restrict__ bb,
                                              float* __restrict__ out,
                                              float* __restrict__ stats) {
    __shared__ float sWa[64 * 32];
    __shared__ float sWb[32 * 32];
    __shared__ float sBa[32], sBb[32];
    __shared__ float sSum[4 * 32], sSq[4 * 32];
    int tid = threadIdx.x;
    for (int i = tid; i < 64 * 32; i += 256) sWa[i] = wa[i];
    for (int i = tid; i < 32 * 32; i += 256) sWb[i] = wb[i];
    if (tid < 32) { sBa[tid] = ba[tid]; sBb[tid] = bb[tid]; }
    __syncthreads();

    int node = blockIdx.x * 256 + tid;
    float r[32];
    if (node < NN) {
        float t[32];
#pragma unroll
        for (int j = 0; j < 32; j++) t[j] = sBa[j];
        const float4* xr = reinterpret_cast<const float4*>(x + (long long)node * 64);
        const float4* ar = reinterpret_cast<const float4*>(agg + (long long)node * 64);
        const float4* w4 = reinterpret_cast<const float4*>(sWa);
        for (int k4 = 0; k4 < 16; k4++) {
            float4 xv = xr[k4];
            float4 av = ar[k4];
            float a0 = xv.x + av.x, a1 = xv.y + av.y, a2 = xv.z + av.z, a3 = xv.w + av.w;
            int kb = k4 * 4;
#pragma unroll
            for (int q = 0; q < 8; q++) {
                float4 w0 = w4[(kb + 0) * 8 + q];
                float4 w1 = w4[(kb + 1) * 8 + q];
                float4 w2 = w4[(kb + 2) * 8 + q];
                float4 w3 = w4[(kb + 3) * 8 + q];
                t[4 * q + 0] += a0 * w0.x + a1 * w1.x + a2 * w2.x + a3 * w3.x;
                t[4 * q + 1] += a0 * w0.y + a1 * w1.y + a2 * w2.y + a3 * w3.y;
                t[4 * q + 2] += a0 * w0.z + a1 * w1.z + a2 * w2.z + a3 * w3.z;
                t[4 * q + 3] += a0 * w0.w + a1 * w1.w + a2 * w2.w + a3 * w3.w;
            }
        }
#pragma unroll
        for (int j = 0; j < 32; j++) t[j] = fmaxf(t[j], 0.f);
#pragma unroll
        for (int j = 0; j < 32; j++) r[j] = sBb[j];
        const float4* v4 = reinterpret_cast<const float4*>(sWb);
        for (int k = 0; k < 32; k++) {
            float a = t[k];
#pragma unroll
            for (int q = 0; q < 8; q++) {
                float4 w = v4[k * 8 + q];
                r[4 * q + 0] += a * w.x;
                r[4 * q + 1] += a * w.y;
                r[4 * q + 2] += a * w.z;
                r[4 * q + 3] += a * w.w;
            }
        }
#pragma unroll
        for (int j = 0; j < 32; j++) r[j] = fmaxf(r[j], 0.f);
        float4* orow = reinterpret_cast<float4*>(out + (long long)node * 32);
#pragma unroll
        for (int q = 0; q < 8; q++) {
            float4 o;
            o.x = r[4 * q]; o.y = r[4 * q + 1]; o.z = r[4 * q + 2]; o.w = r[4 * q + 3];
            orow[q] = o;
        }
    } else {
#pragma unroll
        for (int j = 0; j < 32; j++) r[j] = 0.f;
    }

    int lane = tid & 63, wid = tid >> 6;
#pragma unroll
    for (int j = 0; j < 32; j++) {
        float v = r[j], v2 = v * v;
#pragma unroll
        for (int off = 32; off >= 1; off >>= 1) {
            v += __shfl_down(v, off, 64);
            v2 += __shfl_down(v2, off, 64);
        }
        if (lane == 0) { sSum[wid * 32 + j] = v; sSq[wid * 32 + j] = v2; }
    }
    __syncthreads();
    if (tid < 32) {
        float a = sSum[tid] + sSum[32 + tid] + sSum[64 + tid] + sSum[96 + tid];
        float b = sSq[tid] + sSq[32 + tid] + sSq[64 + tid] + sSq[96 + tid];
        atomicAdd(&stats[tid], a);
        atomicAdd(&stats[32 + tid], b);
    }
}

// ============ layers 2-5 MLP with fused input BN, in-place h update ============
// in = BN(h[n]) + agg[n]; h[n] <- relu(relu(in@wa+ba)@wb+bb); stats_out += ...
__global__ __launch_bounds__(256) void mlp32_bn_k(float* __restrict__ h,
                                                  const float* __restrict__ agg,
                                                  const float* __restrict__ wa,
                                                  const float* __restrict__ ba,
                                                  const float* __restrict__ wb,
                                                  const float* __restrict__ bb,
                                                  const float* __restrict__ st,
                                                  const float* __restrict__ gamma,
                                                  const float* __restrict__ beta,
                                                  float* __restrict__ statsOut) {
    __shared__ float sWa[32 * 32];
    __shared__ float sWb[32 * 32];
    __shared__ float sBa[32], sBb[32];
    __shared__ float sSc[32], sSh[32];
    __shared__ float sSum[4 * 32], sSq[4 * 32];
    int tid = threadIdx.x;
    for (int i = tid; i < 32 * 32; i += 256) { sWa[i] = wa[i]; sWb[i] = wb[i]; }
    if (tid < 32) {
        sBa[tid] = ba[tid]; sBb[tid] = bb[tid];
        const float invn = 1.0f / NN;
        float mu = st[tid] * invn;
        float var = st[32 + tid] * invn - mu * mu;
        float scale = rsqrtf(var + BN_EPS) * gamma[tid];
        sSc[tid] = scale;
        sSh[tid] = beta[tid] - mu * scale;
    }
    __syncthreads();

    int node = blockIdx.x * 256 + tid;
    float r[32];
    if (node < NN) {
        float t[32];
#pragma unroll
        for (int j = 0; j < 32; j++) t[j] = sBa[j];
        const float4* hr = reinterpret_cast<const float4*>(h + (long long)node * 32);
        const float4* ar = reinterpret_cast<const float4*>(agg + (long long)node * 32);
        const float4* w4 = reinterpret_cast<const float4*>(sWa);
        for (int k4 = 0; k4 < 8; k4++) {
            float4 xv = hr[k4];
            float4 av = ar[k4];
            int kb = k4 * 4;
            float a0 = xv.x * sSc[kb + 0] + sSh[kb + 0] + av.x;
            float a1 = xv.y * sSc[kb + 1] + sSh[kb + 1] + av.y;
            float a2 = xv.z * sSc[kb + 2] + sSh[kb + 2] + av.z;
            float a3 = xv.w * sSc[kb + 3] + sSh[kb + 3] + av.w;
#pragma unroll
            for (int q = 0; q < 8; q++) {
                float4 w0 = w4[(kb + 0) * 8 + q];
                float4 w1 = w4[(kb + 1) * 8 + q];
                float4 w2 = w4[(kb + 2) * 8 + q];
                float4 w3 = w4[(kb + 3) * 8 + q];
                t[4 * q + 0] += a0 * w0.x + a1 * w1.x + a2 * w2.x + a3 * w3.x;
                t[4 * q + 1] += a0 * w0.y + a1 * w1.y + a2 * w2.y + a3 * w3.y;
                t[4 * q + 2] += a0 * w0.z + a1 * w1.z + a2 * w2.z + a3 * w3.z;
                t[4 * q + 3] += a0 * w0.w + a1 * w1.w + a2 * w2.w + a3 * w3.w;
            }
        }
#pragma unroll
        for (int j = 0; j < 32; j++) t[j] = fmaxf(t[j], 0.f);
#pragma unroll
        for (int j = 0; j < 32; j++) r[j] = sBb[j];
        const float4* v4 = reinterpret_cast<const float4*>(sWb);
        for (int k = 0; k < 32; k++) {
            float a = t[k];
#pragma unroll
            for (int q = 0; q < 8; q++) {
                float4 w = v4[k * 8 + q];
                r[4 * q + 0] += a * w.x;
                r[4 * q + 1] += a * w.y;
                r[4 * q + 2] += a * w.z;
                r[4 * q + 3] += a * w.w;
            }
        }
#pragma unroll
        for (int j = 0; j < 32; j++) r[j] = fmaxf(r[j], 0.f);
        float4* orow = reinterpret_cast<float4*>(h + (long long)node * 32);
#pragma unroll
        for (int q = 0; q < 8; q++) {
            float4 o;
            o.x = r[4 * q]; o.y = r[4 * q + 1]; o.z = r[4 * q + 2]; o.w = r[4 * q + 3];
            orow[q] = o;
        }
    } else {
#pragma unroll
        for (int j = 0; j < 32; j++) r[j] = 0.f;
    }

    int lane = tid & 63, wid = tid >> 6;
#pragma unroll
    for (int j = 0; j < 32; j++) {
        float v = r[j], v2 = v * v;
#pragma unroll
        for (int off = 32; off >= 1; off >>= 1) {
            v += __shfl_down(v, off, 64);
            v2 += __shfl_down(v2, off, 64);
        }
        if (lane == 0) { sSum[wid * 32 + j] = v; sSq[wid * 32 + j] = v2; }
    }
    __syncthreads();
    if (tid < 32) {
        float a = sSum[tid] + sSum[32 + tid] + sSum[64 + tid] + sSum[96 + tid];
        float b = sSq[tid] + sSq[32 + tid] + sSq[64 + tid] + sSq[96 + tid];
        atomicAdd(&statsOut[tid], a);
        atomicAdd(&statsOut[32 + tid], b);
    }
}

// ============ pool with fused BN of layer 5, privatized atomics ============
#define POOL_NPB 512
__global__ __launch_bounds__(256) void pool_bn_k(const float* __restrict__ h,
                                                 const int* __restrict__ batch,
                                                 const float* __restrict__ st,
                                                 const float* __restrict__ gamma,
                                                 const float* __restrict__ beta,
                                                 float* __restrict__ pooled) {
    int tid = threadIdx.x;
    int f = tid & 31;
    int p = tid >> 5;
    int n0 = blockIdx.x * POOL_NPB + p * (POOL_NPB / 8);
    int n1 = n0 + POOL_NPB / 8;
    if (n1 > NN) n1 = NN;
    if (n0 >= NN) return;
    const float invn = 1.0f / NN;
    float mu = st[f] * invn;
    float var = st[32 + f] * invn - mu * mu;
    float sc = rsqrtf(var + BN_EPS) * gamma[f];
    float sh = beta[f] - mu * sc;
    float acc = 0.f;
    int cur = batch[n0];
    for (int n = n0; n < n1; n++) {
        int g = batch[n];
        if (g != cur) {
            atomicAdd(&pooled[cur * 32 + f], acc);
            cur = g;
            acc = 0.f;
        }
        acc += h[(long long)n * 32 + f] * sc + sh;
    }
    atomicAdd(&pooled[cur * 32 + f], acc);
}

// ============ final FCs ============
__global__ __launch_bounds__(64) void final_k(const float* __restrict__ pooled,
                                              const float* __restrict__ w1,
                                              const float* __restrict__ b1,
                                              const float* __restrict__ w2,
                                              const float* __restrict__ b2,
                                              float* __restrict__ out) {
    int g = threadIdx.x;
    if (g >= NG) return;
    float t[32];
#pragma unroll
    for (int j = 0; j < 32; j++) t[j] = b1[j];
    for (int k = 0; k < 32; k++) {
        float a = pooled[g * 32 + k];
#pragma unroll
        for (int j = 0; j < 32; j++) t[j] += a * w1[k * 32 + j];
    }
#pragma unroll
    for (int j = 0; j < 32; j++) t[j] = fmaxf(t[j], 0.f);
    for (int c = 0; c < NC; c++) {
        float o = b2[c];
#pragma unroll
        for (int k = 0; k < 32; k++) o += t[k] * w2[k * NC + c];
        out[g * NC + c] = o;
    }
}

extern "C" void kernel_launch(void* const* d_in, const int* in_sizes, int n_in,
                              void* d_out, int out_size, void* d_ws, size_t ws_size,
                              hipStream_t stream) {
    const float* x = (const float*)d_in[0];
    const int* ei = (const int*)d_in[1];
    const int* batch = (const int*)d_in[2];
    const float* w1a = (const float*)d_in[3];
    const float* b1a = (const float*)d_in[4];
    const float* w1b = (const float*)d_in[5];
    const float* b1b = (const float*)d_in[6];
    const float* Wa = (const float*)d_in[7];
    const float* Ba = (const float*)d_in[8];
    const float* Wb = (const float*)d_in[9];
    const float* Bb = (const float*)d_in[10];
    const float* bn_gamma = (const float*)d_in[11];
    const float* bn_beta = (const float*)d_in[12];
    const float* fc1w = (const float*)d_in[13];
    const float* fc1b = (const float*)d_in[14];
    const float* fc2w = (const float*)d_in[15];
    const float* fc2b = (const float*)d_in[16];
    float* out = (float*)d_out;

    float* ws = (float*)d_ws;
    float* agg = ws;                                // NN*64
    float* hb = agg + (size_t)NN * 64;              // NN*32
    float* stats_all = hb + (size_t)NN * 32;        // 5*64
    float* pooled = stats_all + 5 * 64;             // NG*32
    int2* binned = (int2*)(pooled + NG * 32);       // NE  (8B aligned: preceding float count is even)
    int* bcnt = (int*)(binned + NE);                // NBUCK
    int* bbase = bcnt + NBUCK;                      // NBUCK+1
    int* bcur = bbase + NBUCK + 1;                  // NBUCK
    int* rowptr = bcur + NBUCK;                     // NN+1
    int* csr = rowptr + NN + 1;                     // NE

    const int nodeBlocks = (NN + 255) / 256;

    // ---- CSR build (bucketed) ----
    hipMemsetAsync(bcnt, 0, NBUCK * sizeof(int), stream);
    binA_k<<<NCH, 256, 0, stream>>>(ei, bcnt);
    binB_k<<<1, 512, 0, stream>>>(bcnt, bbase, bcur);
    binC_k<<<NCH, 256, 0, stream>>>(ei, bcur, binned);
    binD_k<<<NBUCK, 256, 0, stream>>>(binned, bbase, rowptr, csr);

    // ---- zero accumulators ----
    hipMemsetAsync(stats_all, 0, 5 * 64 * sizeof(float), stream);
    hipMemsetAsync(pooled, 0, NG * 32 * sizeof(float), stream);

    // ---- layer 1 (64 feat) ----
    gather64_k<<<NN / 16, 256, 0, stream>>>(x, rowptr, csr, agg);
    mlp1_k<<<nodeBlocks, 256, 0, stream>>>(x, agg, w1a, b1a, w1b, b1b, hb, stats_all);

    // ---- layers 2-5 (32 feat), BN fused into consumers ----
    for (int i = 0; i < 4; i++) {
        const float* st = stats_all + i * 64;
        const float* g = bn_gamma + i * 32;
        const float* be = bn_beta + i * 32;
        gather_bn_k<<<NN / 32, 256, 0, stream>>>(hb, rowptr, csr, agg, st, g, be);
        mlp32_bn_k<<<nodeBlocks, 256, 0, stream>>>(hb, agg, Wa + i * 1024, Ba + i * 32,
                                                   Wb + i * 1024, Bb + i * 32,
                                                   st, g, be, stats_all + (i + 1) * 64);
    }

    // ---- pool (BN5 fused) + FCs ----
    pool_bn_k<<<(NN + POOL_NPB - 1) / POOL_NPB, 256, 0, stream>>>(
        hb, batch, stats_all + 4 * 64, bn_gamma + 4 * 32, bn_beta + 4 * 32, pooled);
    final_k<<<1, 64, 0, stream>>>(pooled, fc1w, fc1b, fc2w, fc2b, out);
}

// Round 5
// 525.271 us; speedup vs baseline: 3.0585x; 1.1221x over previous
//
#include <hip/hip_runtime.h>

#define NN 100000
#define NE 1600000
#define NF 64
#define DM 32
#define NG 64
#define NC 10
#define BN_EPS 1e-5f

#define BSHIFT 8
#define NBUCK ((NN + 255) >> 8)        // 391 buckets of 256 nodes
#define CHUNK 8192                     // edges per binning block
#define NCH ((NE + CHUNK - 1) / CHUNK) // 196

// ============ CSR build via bucket counting-sort ============
__global__ __launch_bounds__(256) void binA_k(const int* __restrict__ ei,
                                              int* __restrict__ bcnt) {
    __shared__ int h[NBUCK];
    for (int i = threadIdx.x; i < NBUCK; i += 256) h[i] = 0;
    __syncthreads();
    long long base = (long long)blockIdx.x * CHUNK;
    int n = (int)((NE - base < CHUNK) ? (NE - base) : CHUNK);
    for (int i = threadIdx.x; i < n; i += 256) {
        int d = ei[NE + base + i];
        atomicAdd(&h[d >> BSHIFT], 1);
    }
    __syncthreads();
    for (int i = threadIdx.x; i < NBUCK; i += 256)
        if (h[i]) atomicAdd(&bcnt[i], h[i]);
}

__global__ __launch_bounds__(512) void binB_k(const int* __restrict__ bcnt,
                                              int* __restrict__ bbase,
                                              int* __restrict__ bcur) {
    __shared__ int s[512];
    int t = threadIdx.x;
    int v = (t < NBUCK) ? bcnt[t] : 0;
    s[t] = v;
    __syncthreads();
    int acc = v;
    for (int off = 1; off < 512; off <<= 1) {
        int add = (t >= off) ? s[t - off] : 0;
        __syncthreads();
        acc += add;
        s[t] = acc;
        __syncthreads();
    }
    if (t < NBUCK) { bbase[t] = acc - v; bcur[t] = acc - v; }
    if (t == 0) bbase[NBUCK] = NE;
}

// C: scatter edges into bucket-grouped array; packed record (src<<8)|localdst
__global__ __launch_bounds__(256) void binC_k(const int* __restrict__ ei,
                                              int* __restrict__ bcur,
                                              unsigned* __restrict__ binned) {
    __shared__ int cnt[NBUCK];
    __shared__ int ofs[NBUCK];
    __shared__ int idx[NBUCK];
    for (int i = threadIdx.x; i < NBUCK; i += 256) { cnt[i] = 0; idx[i] = 0; }
    __syncthreads();
    long long base = (long long)blockIdx.x * CHUNK;
    int n = (int)((NE - base < CHUNK) ? (NE - base) : CHUNK);
    int d[CHUNK / 256];
#pragma unroll
    for (int k = 0; k < CHUNK / 256; k++) {
        int i = threadIdx.x + k * 256;
        int dd = (i < n) ? ei[NE + base + i] : -1;
        d[k] = dd;
        if (dd >= 0) atomicAdd(&cnt[dd >> BSHIFT], 1);
    }
    __syncthreads();
    for (int i = threadIdx.x; i < NBUCK; i += 256)
        if (cnt[i]) ofs[i] = atomicAdd(&bcur[i], cnt[i]);
    __syncthreads();
#pragma unroll
    for (int k = 0; k < CHUNK / 256; k++) {
        int i = threadIdx.x + k * 256;
        if (i < n) {
            unsigned src = (unsigned)ei[base + i];
            int b = d[k] >> BSHIFT;
            int l = atomicAdd(&idx[b], 1);
            binned[ofs[b] + l] = (src << 8) | (unsigned)(d[k] & 255);
        }
    }
}

// D: one block per bucket -> rowptr + csr placement
__global__ __launch_bounds__(256) void binD_k(const unsigned* __restrict__ binned,
                                              const int* __restrict__ bbase,
                                              int* __restrict__ rowptr,
                                              int* __restrict__ csr) {
    __shared__ int cnt[256];
    __shared__ int cur[256];
    __shared__ int s[256];
    int b = blockIdx.x;
    int e0 = bbase[b], e1 = bbase[b + 1];
    int t = threadIdx.x;
    cnt[t] = 0;
    __syncthreads();
    for (int e = e0 + t; e < e1; e += 256) atomicAdd(&cnt[binned[e] & 255u], 1);
    __syncthreads();
    int v = cnt[t];
    s[t] = v;
    __syncthreads();
    int acc = v;
    for (int off = 1; off < 256; off <<= 1) {
        int add = (t >= off) ? s[t - off] : 0;
        __syncthreads();
        acc += add;
        s[t] = acc;
        __syncthreads();
    }
    int base = e0 + acc - v;
    int node = (b << BSHIFT) + t;
    if (node < NN) rowptr[node] = base;
    cur[t] = base;
    if (b == NBUCK - 1 && t == 0) rowptr[NN] = NE;
    __syncthreads();
    for (int e = e0 + t; e < e1; e += 256) {
        unsigned w = binned[e];
        int p = atomicAdd(&cur[w & 255u], 1);
        csr[p] = (int)(w >> 8);
    }
}

// ============ pre-pass layer 1: y = x @ W1a  (no bias) ============
__global__ __launch_bounds__(256) void pre1_k(const float* __restrict__ x,
                                              const float* __restrict__ wa,
                                              float* __restrict__ y) {
    __shared__ float sWa[64 * 32];
    int tid = threadIdx.x;
    for (int i = tid; i < 64 * 32; i += 256) sWa[i] = wa[i];
    __syncthreads();
    int node = blockIdx.x * 256 + tid;
    if (node >= NN) return;
    float t[32];
#pragma unroll
    for (int j = 0; j < 32; j++) t[j] = 0.f;
    const float4* xr = reinterpret_cast<const float4*>(x + (long long)node * 64);
    const float4* w4 = reinterpret_cast<const float4*>(sWa);
    for (int k4 = 0; k4 < 16; k4++) {
        float4 xv = xr[k4];
        int kb = k4 * 4;
#pragma unroll
        for (int q = 0; q < 8; q++) {
            float4 w0 = w4[(kb + 0) * 8 + q];
            float4 w1 = w4[(kb + 1) * 8 + q];
            float4 w2 = w4[(kb + 2) * 8 + q];
            float4 w3 = w4[(kb + 3) * 8 + q];
            t[4 * q + 0] += xv.x * w0.x + xv.y * w1.x + xv.z * w2.x + xv.w * w3.x;
            t[4 * q + 1] += xv.x * w0.y + xv.y * w1.y + xv.z * w2.y + xv.w * w3.y;
            t[4 * q + 2] += xv.x * w0.z + xv.y * w1.z + xv.z * w2.z + xv.w * w3.z;
            t[4 * q + 3] += xv.x * w0.w + xv.y * w1.w + xv.z * w2.w + xv.w * w3.w;
        }
    }
    float4* yr = reinterpret_cast<float4*>(y + (long long)node * 32);
#pragma unroll
    for (int q = 0; q < 8; q++) {
        float4 o;
        o.x = t[4 * q]; o.y = t[4 * q + 1]; o.z = t[4 * q + 2]; o.w = t[4 * q + 3];
        yr[q] = o;
    }
}

// ============ plain gather (F=32), 8 lanes/node, edge loop unrolled x2 ============
__global__ __launch_bounds__(256) void gather32_k(const float* __restrict__ y,
                                                  const int* __restrict__ rowptr,
                                                  const int* __restrict__ csr,
                                                  float* __restrict__ agg) {
    int tid = threadIdx.x;
    int node = blockIdx.x * 32 + tid / 8;
    int l = tid % 8;
    if (node >= NN) return;
    int s = rowptr[node], e = rowptr[node + 1];
    const float4* y4 = reinterpret_cast<const float4*>(y);
    float4 a0 = make_float4(0.f, 0.f, 0.f, 0.f);
    float4 a1 = make_float4(0.f, 0.f, 0.f, 0.f);
    int i = s;
    for (; i + 2 <= e; i += 2) {
        int s0 = csr[i], s1 = csr[i + 1];
        float4 v0 = y4[(long long)s0 * 8 + l];
        float4 v1 = y4[(long long)s1 * 8 + l];
        a0.x += v0.x; a0.y += v0.y; a0.z += v0.z; a0.w += v0.w;
        a1.x += v1.x; a1.y += v1.y; a1.z += v1.z; a1.w += v1.w;
    }
    if (i < e) {
        float4 v = y4[(long long)csr[i] * 8 + l];
        a0.x += v.x; a0.y += v.y; a0.z += v.z; a0.w += v.w;
    }
    a0.x += a1.x; a0.y += a1.y; a0.z += a1.z; a0.w += a1.w;
    reinterpret_cast<float4*>(agg)[(long long)node * 8 + l] = a0;
}

// ============ gather with fused BN of previous layer (F=32), unrolled x2 ============
__global__ __launch_bounds__(256) void gather_bn_k(const float* __restrict__ h,
                                                   const int* __restrict__ rowptr,
                                                   const int* __restrict__ csr,
                                                   float* __restrict__ agg,
                                                   const float* __restrict__ st,
                                                   const float* __restrict__ gamma,
                                                   const float* __restrict__ beta) {
    int tid = threadIdx.x;
    int node = blockIdx.x * 32 + tid / 8;
    int l = tid % 8;
    if (node >= NN) return;
    const float invn = 1.0f / NN;
    float sc[4], sh[4];
#pragma unroll
    for (int c = 0; c < 4; c++) {
        int f = 4 * l + c;
        float mu = st[f] * invn;
        float var = st[32 + f] * invn - mu * mu;
        float scale = rsqrtf(var + BN_EPS) * gamma[f];
        sc[c] = scale;
        sh[c] = beta[f] - mu * scale;
    }
    int s = rowptr[node], e = rowptr[node + 1];
    const float4* h4 = reinterpret_cast<const float4*>(h);
    float4 a0 = make_float4(0.f, 0.f, 0.f, 0.f);
    float4 a1 = make_float4(0.f, 0.f, 0.f, 0.f);
    int i = s;
    for (; i + 2 <= e; i += 2) {
        int s0 = csr[i], s1 = csr[i + 1];
        float4 v0 = h4[(long long)s0 * 8 + l];
        float4 v1 = h4[(long long)s1 * 8 + l];
        a0.x += v0.x; a0.y += v0.y; a0.z += v0.z; a0.w += v0.w;
        a1.x += v1.x; a1.y += v1.y; a1.z += v1.z; a1.w += v1.w;
    }
    if (i < e) {
        float4 v = h4[(long long)csr[i] * 8 + l];
        a0.x += v.x; a0.y += v.y; a0.z += v.z; a0.w += v.w;
    }
    a0.x += a1.x; a0.y += a1.y; a0.z += a1.z; a0.w += a1.w;
    float deg = (float)(e - s);
    a0.x = a0.x * sc[0] + deg * sh[0];
    a0.y = a0.y * sc[1] + deg * sh[1];
    a0.z = a0.z * sc[2] + deg * sh[2];
    a0.w = a0.w * sc[3] + deg * sh[3];
    reinterpret_cast<float4*>(agg)[(long long)node * 8 + l] = a0;
}

// ============ layer 1 tail: t=relu(y+agg+ba); h=relu(t@Wb+bb); BN stats ============
__global__ __launch_bounds__(256) void mlp1b_k(const float* __restrict__ y,
                                               const float* __restrict__ agg,
                                               const float* __restrict__ ba,
                                               const float* __restrict__ wb,
                                               const float* __restrict__ bb,
                                               float* __restrict__ out,
                                               float* __restrict__ stats) {
    __shared__ float sWb[32 * 32];
    __shared__ float sBa[32], sBb[32];
    __shared__ float sSum[4 * 32], sSq[4 * 32];
    int tid = threadIdx.x;
    for (int i = tid; i < 32 * 32; i += 256) sWb[i] = wb[i];
    if (tid < 32) { sBa[tid] = ba[tid]; sBb[tid] = bb[tid]; }
    __syncthreads();

    int node = blockIdx.x * 256 + tid;
    float r[32];
    if (node < NN) {
        const float4* yr = reinterpret_cast<const float4*>(y + (long long)node * 32);
        const float4* ar = reinterpret_cast<const float4*>(agg + (long long)node * 32);
#pragma unroll
        for (int j = 0; j < 32; j++) r[j] = sBb[j];
        const float4* v4 = reinterpret_cast<const float4*>(sWb);
        for (int k4 = 0; k4 < 8; k4++) {
            float4 yv = yr[k4];
            float4 av = ar[k4];
            int kb = k4 * 4;
            float t0 = fmaxf(yv.x + av.x + sBa[kb + 0], 0.f);
            float t1 = fmaxf(yv.y + av.y + sBa[kb + 1], 0.f);
            float t2 = fmaxf(yv.z + av.z + sBa[kb + 2], 0.f);
            float t3 = fmaxf(yv.w + av.w + sBa[kb + 3], 0.f);
#pragma unroll
            for (int q = 0; q < 8; q++) {
                float4 w0 = v4[(kb + 0) * 8 + q];
                float4 w1 = v4[(kb + 1) * 8 + q];
                float4 w2 = v4[(kb + 2) * 8 + q];
                float4 w3 = v4[(kb + 3) * 8 + q];
                r[4 * q + 0] += t0 * w0.x + t1 * w1.x + t2 * w2.x + t3 * w3.x;
                r[4 * q + 1] += t0 * w0.y + t1 * w1.y + t2 * w2.y + t3 * w3.y;
                r[4 * q + 2] += t0 * w0.z + t1 * w1.z + t2 * w2.z + t3 * w3.z;
                r[4 * q + 3] += t0 * w0.w + t1 * w1.w + t2 * w2.w + t3 * w3.w;
            }
        }
#pragma unroll
        for (int j = 0; j < 32; j++) r[j] = fmaxf(r[j], 0.f);
        float4* orow = reinterpret_cast<float4*>(out + (long long)node * 32);
#pragma unroll
        for (int q = 0; q < 8; q++) {
            float4 o;
            o.x = r[4 * q]; o.y = r[4 * q + 1]; o.z = r[4 * q + 2]; o.w = r[4 * q + 3];
            orow[q] = o;
        }
    } else {
#pragma unroll
        for (int j = 0; j < 32; j++) r[j] = 0.f;
    }

    int lane = tid & 63, wid = tid >> 6;
#pragma unroll
    for (int j = 0; j < 32; j++) {
        float v = r[j], v2 = v * v;
#pragma unroll
        for (int off = 32; off >= 1; off >>= 1) {
            v += __shfl_down(v, off, 64);
            v2 += __shfl_down(v2, off, 64);
        }
        if (lane == 0) { sSum[wid * 32 + j] = v; sSq[wid * 32 + j] = v2; }
    }
    __syncthreads();
    if (tid < 32) {
        float a = sSum[tid] + sSum[32 + tid] + sSum[64 + tid] + sSum[96 + tid];
        float b = sSq[tid] + sSq[32 + tid] + sSq[64 + tid] + sSq[96 + tid];
        atomicAdd(&stats[tid], a);
        atomicAdd(&stats[32 + tid], b);
    }
}

// ============ layers 2-5 MLP with fused input BN, in-place h update ============
__global__ __launch_bounds__(256) void mlp32_bn_k(float* __restrict__ h,
                                                  const float* __restrict__ agg,
                                                  const float* __restrict__ wa,
                                                  const float* __restrict__ ba,
                                                  const float* __restrict__ wb,
                                                  const float* __restrict__ bb,
                                                  const float* __restrict__ st,
                                                  const float* __restrict__ gamma,
                                                  const float* __restrict__ beta,
                                                  float* __restrict__ statsOut) {
    __shared__ float sWa[32 * 32];
    __shared__ float sWb[32 * 32];
    __shared__ float sBa[32], sBb[32];
    __shared__ float sSc[32], sSh[32];
    __shared__ float sSum[4 * 32], sSq[4 * 32];
    int tid = threadIdx.x;
    for (int i = tid; i < 32 * 32; i += 256) { sWa[i] = wa[i]; sWb[i] = wb[i]; }
    if (tid < 32) {
        sBa[tid] = ba[tid]; sBb[tid] = bb[tid];
        const float invn = 1.0f / NN;
        float mu = st[tid] * invn;
        float var = st[32 + tid] * invn - mu * mu;
        float scale = rsqrtf(var + BN_EPS) * gamma[tid];
        sSc[tid] = scale;
        sSh[tid] = beta[tid] - mu * scale;
    }
    __syncthreads();

    int node = blockIdx.x * 256 + tid;
    float r[32];
    if (node < NN) {
        float t[32];
#pragma unroll
        for (int j = 0; j < 32; j++) t[j] = sBa[j];
        const float4* hr = reinterpret_cast<const float4*>(h + (long long)node * 32);
        const float4* ar = reinterpret_cast<const float4*>(agg + (long long)node * 32);
        const float4* w4 = reinterpret_cast<const float4*>(sWa);
        for (int k4 = 0; k4 < 8; k4++) {
            float4 xv = hr[k4];
            float4 av = ar[k4];
            int kb = k4 * 4;
            float a0 = xv.x * sSc[kb + 0] + sSh[kb + 0] + av.x;
            float a1 = xv.y * sSc[kb + 1] + sSh[kb + 1] + av.y;
            float a2 = xv.z * sSc[kb + 2] + sSh[kb + 2] + av.z;
            float a3 = xv.w * sSc[kb + 3] + sSh[kb + 3] + av.w;
#pragma unroll
            for (int q = 0; q < 8; q++) {
                float4 w0 = w4[(kb + 0) * 8 + q];
                float4 w1 = w4[(kb + 1) * 8 + q];
                float4 w2 = w4[(kb + 2) * 8 + q];
                float4 w3 = w4[(kb + 3) * 8 + q];
                t[4 * q + 0] += a0 * w0.x + a1 * w1.x + a2 * w2.x + a3 * w3.x;
                t[4 * q + 1] += a0 * w0.y + a1 * w1.y + a2 * w2.y + a3 * w3.y;
                t[4 * q + 2] += a0 * w0.z + a1 * w1.z + a2 * w2.z + a3 * w3.z;
                t[4 * q + 3] += a0 * w0.w + a1 * w1.w + a2 * w2.w + a3 * w3.w;
            }
        }
#pragma unroll
        for (int j = 0; j < 32; j++) t[j] = fmaxf(t[j], 0.f);
#pragma unroll
        for (int j = 0; j < 32; j++) r[j] = sBb[j];
        const float4* v4 = reinterpret_cast<const float4*>(sWb);
        for (int k = 0; k < 32; k++) {
            float a = t[k];
#pragma unroll
            for (int q = 0; q < 8; q++) {
                float4 w = v4[k * 8 + q];
                r[4 * q + 0] += a * w.x;
                r[4 * q + 1] += a * w.y;
                r[4 * q + 2] += a * w.z;
                r[4 * q + 3] += a * w.w;
            }
        }
#pragma unroll
        for (int j = 0; j < 32; j++) r[j] = fmaxf(r[j], 0.f);
        float4* orow = reinterpret_cast<float4*>(h + (long long)node * 32);
#pragma unroll
        for (int q = 0; q < 8; q++) {
            float4 o;
            o.x = r[4 * q]; o.y = r[4 * q + 1]; o.z = r[4 * q + 2]; o.w = r[4 * q + 3];
            orow[q] = o;
        }
    } else {
#pragma unroll
        for (int j = 0; j < 32; j++) r[j] = 0.f;
    }

    int lane = tid & 63, wid = tid >> 6;
#pragma unroll
    for (int j = 0; j < 32; j++) {
        float v = r[j], v2 = v * v;
#pragma unroll
        for (int off = 32; off >= 1; off >>= 1) {
            v += __shfl_down(v, off, 64);
            v2 += __shfl_down(v2, off, 64);
        }
        if (lane == 0) { sSum[wid * 32 + j] = v; sSq[wid * 32 + j] = v2; }
    }
    __syncthreads();
    if (tid < 32) {
        float a = sSum[tid] + sSum[32 + tid] + sSum[64 + tid] + sSum[96 + tid];
        float b = sSq[tid] + sSq[32 + tid] + sSq[64 + tid] + sSq[96 + tid];
        atomicAdd(&statsOut[tid], a);
        atomicAdd(&statsOut[32 + tid], b);
    }
}

// ============ pool with fused BN of layer 5, privatized atomics ============
#define POOL_NPB 512
__global__ __launch_bounds__(256) void pool_bn_k(const float* __restrict__ h,
                                                 const int* __restrict__ batch,
                                                 const float* __restrict__ st,
                                                 const float* __restrict__ gamma,
                                                 const float* __restrict__ beta,
                                                 float* __restrict__ pooled) {
    int tid = threadIdx.x;
    int f = tid & 31;
    int p = tid >> 5;
    int n0 = blockIdx.x * POOL_NPB + p * (POOL_NPB / 8);
    int n1 = n0 + POOL_NPB / 8;
    if (n1 > NN) n1 = NN;
    if (n0 >= NN) return;
    const float invn = 1.0f / NN;
    float mu = st[f] * invn;
    float var = st[32 + f] * invn - mu * mu;
    float sc = rsqrtf(var + BN_EPS) * gamma[f];
    float sh = beta[f] - mu * sc;
    float acc = 0.f;
    int cur = batch[n0];
    for (int n = n0; n < n1; n++) {
        int g = batch[n];
        if (g != cur) {
            atomicAdd(&pooled[cur * 32 + f], acc);
            cur = g;
            acc = 0.f;
        }
        acc += h[(long long)n * 32 + f] * sc + sh;
    }
    atomicAdd(&pooled[cur * 32 + f], acc);
}

// ============ final FCs ============
__global__ __launch_bounds__(64) void final_k(const float* __restrict__ pooled,
                                              const float* __restrict__ w1,
                                              const float* __restrict__ b1,
                                              const float* __restrict__ w2,
                                              const float* __restrict__ b2,
                                              float* __restrict__ out) {
    int g = threadIdx.x;
    if (g >= NG) return;
    float t[32];
#pragma unroll
    for (int j = 0; j < 32; j++) t[j] = b1[j];
    for (int k = 0; k < 32; k++) {
        float a = pooled[g * 32 + k];
#pragma unroll
        for (int j = 0; j < 32; j++) t[j] += a * w1[k * 32 + j];
    }
#pragma unroll
    for (int j = 0; j < 32; j++) t[j] = fmaxf(t[j], 0.f);
    for (int c = 0; c < NC; c++) {
        float o = b2[c];
#pragma unroll
        for (int k = 0; k < 32; k++) o += t[k] * w2[k * NC + c];
        out[g * NC + c] = o;
    }
}

extern "C" void kernel_launch(void* const* d_in, const int* in_sizes, int n_in,
                              void* d_out, int out_size, void* d_ws, size_t ws_size,
                              hipStream_t stream) {
    const float* x = (const float*)d_in[0];
    const int* ei = (const int*)d_in[1];
    const int* batch = (const int*)d_in[2];
    const float* w1a = (const float*)d_in[3];
    const float* b1a = (const float*)d_in[4];
    const float* w1b = (const float*)d_in[5];
    const float* b1b = (const float*)d_in[6];
    const float* Wa = (const float*)d_in[7];
    const float* Ba = (const float*)d_in[8];
    const float* Wb = (const float*)d_in[9];
    const float* Bb = (const float*)d_in[10];
    const float* bn_gamma = (const float*)d_in[11];
    const float* bn_beta = (const float*)d_in[12];
    const float* fc1w = (const float*)d_in[13];
    const float* fc1b = (const float*)d_in[14];
    const float* fc2w = (const float*)d_in[15];
    const float* fc2b = (const float*)d_in[16];
    float* out = (float*)d_out;

    float* ws = (float*)d_ws;
    float* y = ws;                                  // NN*32  (x @ W1a)
    float* hb = y + (size_t)NN * 32;                // NN*32
    float* agg = hb + (size_t)NN * 32;              // NN*32
    float* stats_all = agg + (size_t)NN * 32;       // 5*64
    float* pooled = stats_all + 5 * 64;             // NG*32
    unsigned* binned = (unsigned*)(pooled + NG * 32); // NE
    int* bcnt = (int*)(binned + NE);                // NBUCK
    int* bbase = bcnt + NBUCK;                      // NBUCK+1
    int* bcur = bbase + NBUCK + 1;                  // NBUCK
    int* rowptr = bcur + NBUCK;                     // NN+1
    int* csr = rowptr + NN + 1;                     // NE

    const int nodeBlocks = (NN + 255) / 256;
    const int gBlocks = (NN + 31) / 32;

    // ---- CSR build (bucketed, packed) ----
    hipMemsetAsync(bcnt, 0, NBUCK * sizeof(int), stream);
    binA_k<<<NCH, 256, 0, stream>>>(ei, bcnt);
    binB_k<<<1, 512, 0, stream>>>(bcnt, bbase, bcur);
    binC_k<<<NCH, 256, 0, stream>>>(ei, bcur, binned);
    binD_k<<<NBUCK, 256, 0, stream>>>(binned, bbase, rowptr, csr);

    // ---- zero accumulators ----
    hipMemsetAsync(stats_all, 0, (5 * 64 + NG * 32) * sizeof(float), stream);

    // ---- layer 1 via algebraic transform: y = x@Wa; agg = gather(y) ----
    pre1_k<<<nodeBlocks, 256, 0, stream>>>(x, w1a, y);
    gather32_k<<<gBlocks, 256, 0, stream>>>(y, rowptr, csr, agg);
    mlp1b_k<<<nodeBlocks, 256, 0, stream>>>(y, agg, b1a, w1b, b1b, hb, stats_all);

    // ---- layers 2-5 (32 feat), BN fused into consumers ----
    for (int i = 0; i < 4; i++) {
        const float* st = stats_all + i * 64;
        const float* g = bn_gamma + i * 32;
        const float* be = bn_beta + i * 32;
        gather_bn_k<<<gBlocks, 256, 0, stream>>>(hb, rowptr, csr, agg, st, g, be);
        mlp32_bn_k<<<nodeBlocks, 256, 0, stream>>>(hb, agg, Wa + i * 1024, Ba + i * 32,
                                                   Wb + i * 1024, Bb + i * 32,
                                                   st, g, be, stats_all + (i + 1) * 64);
    }

    // ---- pool (BN5 fused) + FCs ----
    pool_bn_k<<<(NN + POOL_NPB - 1) / POOL_NPB, 256, 0, stream>>>(
        hb, batch, stats_all + 4 * 64, bn_gamma + 4 * 32, bn_beta + 4 * 32, pooled);
    final_k<<<1, 64, 0, stream>>>(pooled, fc1w, fc1b, fc2w, fc2b, out);
}

// Round 7
// 504.508 us; speedup vs baseline: 3.1843x; 1.0412x over previous
//
#include <hip/hip_runtime.h>
#include <hip/hip_fp16.h>

#define NN 100000
#define NE 1600000
#define NF 64
#define DM 32
#define NG 64
#define NC 10
#define BN_EPS 1e-5f

#define BSHIFT 8
#define NBUCK ((NN + 255) >> 8)        // 391 buckets of 256 nodes
#define CHUNK 8192                     // edges per binning block
#define NCH ((NE + CHUNK - 1) / CHUNK) // 196

// ---- fp16 pack/unpack helpers (RNE) ----
__device__ __forceinline__ float2 up2(unsigned u) {
    __half2 h = __builtin_bit_cast(__half2, u);
    return __half22float2(h);
}
__device__ __forceinline__ unsigned pk2(float a, float b) {
    __half2 h = __floats2half2_rn(a, b);
    return __builtin_bit_cast(unsigned, h);
}

// ============ CSR build via bucket counting-sort ============
__global__ __launch_bounds__(256) void binA_k(const int* __restrict__ ei,
                                              int* __restrict__ bcnt) {
    __shared__ int h[NBUCK];
    for (int i = threadIdx.x; i < NBUCK; i += 256) h[i] = 0;
    __syncthreads();
    long long base = (long long)blockIdx.x * CHUNK;
    int n = (int)((NE - base < CHUNK) ? (NE - base) : CHUNK);
    for (int i = threadIdx.x; i < n; i += 256) {
        int d = ei[NE + base + i];
        atomicAdd(&h[d >> BSHIFT], 1);
    }
    __syncthreads();
    for (int i = threadIdx.x; i < NBUCK; i += 256)
        if (h[i]) atomicAdd(&bcnt[i], h[i]);
}

__global__ __launch_bounds__(512) void binB_k(const int* __restrict__ bcnt,
                                              int* __restrict__ bbase,
                                              int* __restrict__ bcur) {
    __shared__ int s[512];
    int t = threadIdx.x;
    int v = (t < NBUCK) ? bcnt[t] : 0;
    s[t] = v;
    __syncthreads();
    int acc = v;
    for (int off = 1; off < 512; off <<= 1) {
        int add = (t >= off) ? s[t - off] : 0;
        __syncthreads();
        acc += add;
        s[t] = acc;
        __syncthreads();
    }
    if (t < NBUCK) { bbase[t] = acc - v; bcur[t] = acc - v; }
    if (t == 0) bbase[NBUCK] = NE;
}

__global__ __launch_bounds__(256) void binC_k(const int* __restrict__ ei,
                                              int* __restrict__ bcur,
                                              unsigned* __restrict__ binned) {
    __shared__ int cnt[NBUCK];
    __shared__ int ofs[NBUCK];
    __shared__ int idx[NBUCK];
    for (int i = threadIdx.x; i < NBUCK; i += 256) { cnt[i] = 0; idx[i] = 0; }
    __syncthreads();
    long long base = (long long)blockIdx.x * CHUNK;
    int n = (int)((NE - base < CHUNK) ? (NE - base) : CHUNK);
    int d[CHUNK / 256];
#pragma unroll
    for (int k = 0; k < CHUNK / 256; k++) {
        int i = threadIdx.x + k * 256;
        int dd = (i < n) ? ei[NE + base + i] : -1;
        d[k] = dd;
        if (dd >= 0) atomicAdd(&cnt[dd >> BSHIFT], 1);
    }
    __syncthreads();
    for (int i = threadIdx.x; i < NBUCK; i += 256)
        if (cnt[i]) ofs[i] = atomicAdd(&bcur[i], cnt[i]);
    __syncthreads();
#pragma unroll
    for (int k = 0; k < CHUNK / 256; k++) {
        int i = threadIdx.x + k * 256;
        if (i < n) {
            unsigned src = (unsigned)ei[base + i];
            int b = d[k] >> BSHIFT;
            int l = atomicAdd(&idx[b], 1);
            binned[ofs[b] + l] = (src << 8) | (unsigned)(d[k] & 255);
        }
    }
}

__global__ __launch_bounds__(256) void binD_k(const unsigned* __restrict__ binned,
                                              const int* __restrict__ bbase,
                                              int* __restrict__ rowptr,
                                              int* __restrict__ csr) {
    __shared__ int cnt[256];
    __shared__ int cur[256];
    __shared__ int s[256];
    int b = blockIdx.x;
    int e0 = bbase[b], e1 = bbase[b + 1];
    int t = threadIdx.x;
    cnt[t] = 0;
    __syncthreads();
    for (int e = e0 + t; e < e1; e += 256) atomicAdd(&cnt[binned[e] & 255u], 1);
    __syncthreads();
    int v = cnt[t];
    s[t] = v;
    __syncthreads();
    int acc = v;
    for (int off = 1; off < 256; off <<= 1) {
        int add = (t >= off) ? s[t - off] : 0;
        __syncthreads();
        acc += add;
        s[t] = acc;
        __syncthreads();
    }
    int base = e0 + acc - v;
    int node = (b << BSHIFT) + t;
    if (node < NN) rowptr[node] = base;
    cur[t] = base;
    if (b == NBUCK - 1 && t == 0) rowptr[NN] = NE;
    __syncthreads();
    for (int e = e0 + t; e < e1; e += 256) {
        unsigned w = binned[e];
        int p = atomicAdd(&cur[w & 255u], 1);
        csr[p] = (int)(w >> 8);
    }
}

// ============ pre-pass layer 1: y = x @ W1a; also emits fp16 copy; zeroes accumulators ============
__global__ __launch_bounds__(256) void pre1_k(const float* __restrict__ x,
                                              const float* __restrict__ wa,
                                              float* __restrict__ y,
                                              unsigned* __restrict__ yhf,
                                              float* __restrict__ zbuf) {
    __shared__ float sWa[64 * 32];
    int tid = threadIdx.x;
    if (blockIdx.x == 0) {
        for (int i = tid; i < 5 * 64 + NG * 32; i += 256) zbuf[i] = 0.f;
    }
    for (int i = tid; i < 64 * 32; i += 256) sWa[i] = wa[i];
    __syncthreads();
    int node = blockIdx.x * 256 + tid;
    if (node >= NN) return;
    float t[32];
#pragma unroll
    for (int j = 0; j < 32; j++) t[j] = 0.f;
    const float4* xr = reinterpret_cast<const float4*>(x + (long long)node * 64);
    const float4* w4 = reinterpret_cast<const float4*>(sWa);
    for (int k4 = 0; k4 < 16; k4++) {
        float4 xv = xr[k4];
        int kb = k4 * 4;
#pragma unroll
        for (int q = 0; q < 8; q++) {
            float4 w0 = w4[(kb + 0) * 8 + q];
            float4 w1 = w4[(kb + 1) * 8 + q];
            float4 w2 = w4[(kb + 2) * 8 + q];
            float4 w3 = w4[(kb + 3) * 8 + q];
            t[4 * q + 0] += xv.x * w0.x + xv.y * w1.x + xv.z * w2.x + xv.w * w3.x;
            t[4 * q + 1] += xv.x * w0.y + xv.y * w1.y + xv.z * w2.y + xv.w * w3.y;
            t[4 * q + 2] += xv.x * w0.z + xv.y * w1.z + xv.z * w2.z + xv.w * w3.z;
            t[4 * q + 3] += xv.x * w0.w + xv.y * w1.w + xv.z * w2.w + xv.w * w3.w;
        }
    }
    float4* yr = reinterpret_cast<float4*>(y + (long long)node * 32);
#pragma unroll
    for (int q = 0; q < 8; q++) {
        float4 o;
        o.x = t[4 * q]; o.y = t[4 * q + 1]; o.z = t[4 * q + 2]; o.w = t[4 * q + 3];
        yr[q] = o;
    }
    uint4* yb = reinterpret_cast<uint4*>(yhf) + (long long)node * 4;
#pragma unroll
    for (int g = 0; g < 4; g++) {
        uint4 p;
        p.x = pk2(t[8 * g + 0], t[8 * g + 1]);
        p.y = pk2(t[8 * g + 2], t[8 * g + 3]);
        p.z = pk2(t[8 * g + 4], t[8 * g + 5]);
        p.w = pk2(t[8 * g + 6], t[8 * g + 7]);
        yb[g] = p;
    }
}

// ============ fp16 gather: 4 lanes/node, 16B/lane, unroll x4, fp32 accum ============
// BN==true: agg = sc * sum(fp16(h_j)) + deg * sh   (BN of prev layer fused, post-sum)
template <bool BN>
__global__ __launch_bounds__(256) void gatherH_k(const unsigned* __restrict__ thf,
                                                 const int* __restrict__ rowptr,
                                                 const int* __restrict__ csr,
                                                 float* __restrict__ agg,
                                                 const float* __restrict__ st,
                                                 const float* __restrict__ gamma,
                                                 const float* __restrict__ beta) {
    int tid = threadIdx.x;
    int node = blockIdx.x * 64 + (tid >> 2);
    int l = tid & 3;                         // feats l*8 .. l*8+7
    if (node >= NN) return;
    float sc[8], sh[8];
    if (BN) {
        const float invn = 1.0f / NN;
#pragma unroll
        for (int c = 0; c < 8; c++) {
            int f = 8 * l + c;
            float mu = st[f] * invn;
            float var = st[32 + f] * invn - mu * mu;
            float scale = rsqrtf(var + BN_EPS) * gamma[f];
            sc[c] = scale;
            sh[c] = beta[f] - mu * scale;
        }
    }
    int s = rowptr[node], e = rowptr[node + 1];
    const uint4* t4 = reinterpret_cast<const uint4*>(thf);
    float a[8];
#pragma unroll
    for (int c = 0; c < 8; c++) a[c] = 0.f;
    int i = s;
    for (; i + 4 <= e; i += 4) {
        int s0 = csr[i], s1 = csr[i + 1], s2 = csr[i + 2], s3 = csr[i + 3];
        uint4 w0 = t4[(long long)s0 * 4 + l];
        uint4 w1 = t4[(long long)s1 * 4 + l];
        uint4 w2 = t4[(long long)s2 * 4 + l];
        uint4 w3 = t4[(long long)s3 * 4 + l];
        float2 p;
        p = up2(w0.x); a[0] += p.x; a[1] += p.y;
        p = up2(w0.y); a[2] += p.x; a[3] += p.y;
        p = up2(w0.z); a[4] += p.x; a[5] += p.y;
        p = up2(w0.w); a[6] += p.x; a[7] += p.y;
        p = up2(w1.x); a[0] += p.x; a[1] += p.y;
        p = up2(w1.y); a[2] += p.x; a[3] += p.y;
        p = up2(w1.z); a[4] += p.x; a[5] += p.y;
        p = up2(w1.w); a[6] += p.x; a[7] += p.y;
        p = up2(w2.x); a[0] += p.x; a[1] += p.y;
        p = up2(w2.y); a[2] += p.x; a[3] += p.y;
        p = up2(w2.z); a[4] += p.x; a[5] += p.y;
        p = up2(w2.w); a[6] += p.x; a[7] += p.y;
        p = up2(w3.x); a[0] += p.x; a[1] += p.y;
        p = up2(w3.y); a[2] += p.x; a[3] += p.y;
        p = up2(w3.z); a[4] += p.x; a[5] += p.y;
        p = up2(w3.w); a[6] += p.x; a[7] += p.y;
    }
    for (; i < e; i++) {
        uint4 w = t4[(long long)csr[i] * 4 + l];
        float2 p;
        p = up2(w.x); a[0] += p.x; a[1] += p.y;
        p = up2(w.y); a[2] += p.x; a[3] += p.y;
        p = up2(w.z); a[4] += p.x; a[5] += p.y;
        p = up2(w.w); a[6] += p.x; a[7] += p.y;
    }
    if (BN) {
        float deg = (float)(e - s);
#pragma unroll
        for (int c = 0; c < 8; c++) a[c] = a[c] * sc[c] + deg * sh[c];
    }
    float4* ar = reinterpret_cast<float4*>(agg + (long long)node * 32 + l * 8);
    float4 o0, o1;
    o0.x = a[0]; o0.y = a[1]; o0.z = a[2]; o0.w = a[3];
    o1.x = a[4]; o1.y = a[5]; o1.z = a[6]; o1.w = a[7];
    ar[0] = o0;
    ar[1] = o1;
}

// ============ layer 1 tail: t=relu(y+agg+ba); h=relu(t@Wb+bb); BN stats; fp16 copy ============
__global__ __launch_bounds__(256) void mlp1b_k(const float* __restrict__ y,
                                               const float* __restrict__ agg,
                                               const float* __restrict__ ba,
                                               const float* __restrict__ wb,
                                               const float* __restrict__ bb,
                                               float* __restrict__ out,
                                               unsigned* __restrict__ outhf,
                                               float* __restrict__ stats) {
    __shared__ float sWb[32 * 32];
    __shared__ float sBa[32], sBb[32];
    __shared__ float sSum[4 * 32], sSq[4 * 32];
    int tid = threadIdx.x;
    for (int i = tid; i < 32 * 32; i += 256) sWb[i] = wb[i];
    if (tid < 32) { sBa[tid] = ba[tid]; sBb[tid] = bb[tid]; }
    __syncthreads();

    int node = blockIdx.x * 256 + tid;
    float r[32];
    if (node < NN) {
        const float4* yr = reinterpret_cast<const float4*>(y + (long long)node * 32);
        const float4* ar = reinterpret_cast<const float4*>(agg + (long long)node * 32);
#pragma unroll
        for (int j = 0; j < 32; j++) r[j] = sBb[j];
        const float4* v4 = reinterpret_cast<const float4*>(sWb);
        for (int k4 = 0; k4 < 8; k4++) {
            float4 yv = yr[k4];
            float4 av = ar[k4];
            int kb = k4 * 4;
            float t0 = fmaxf(yv.x + av.x + sBa[kb + 0], 0.f);
            float t1 = fmaxf(yv.y + av.y + sBa[kb + 1], 0.f);
            float t2 = fmaxf(yv.z + av.z + sBa[kb + 2], 0.f);
            float t3 = fmaxf(yv.w + av.w + sBa[kb + 3], 0.f);
#pragma unroll
            for (int q = 0; q < 8; q++) {
                float4 w0 = v4[(kb + 0) * 8 + q];
                float4 w1 = v4[(kb + 1) * 8 + q];
                float4 w2 = v4[(kb + 2) * 8 + q];
                float4 w3 = v4[(kb + 3) * 8 + q];
                r[4 * q + 0] += t0 * w0.x + t1 * w1.x + t2 * w2.x + t3 * w3.x;
                r[4 * q + 1] += t0 * w0.y + t1 * w1.y + t2 * w2.y + t3 * w3.y;
                r[4 * q + 2] += t0 * w0.z + t1 * w1.z + t2 * w2.z + t3 * w3.z;
                r[4 * q + 3] += t0 * w0.w + t1 * w1.w + t2 * w2.w + t3 * w3.w;
            }
        }
#pragma unroll
        for (int j = 0; j < 32; j++) r[j] = fmaxf(r[j], 0.f);
        float4* orow = reinterpret_cast<float4*>(out + (long long)node * 32);
#pragma unroll
        for (int q = 0; q < 8; q++) {
            float4 o;
            o.x = r[4 * q]; o.y = r[4 * q + 1]; o.z = r[4 * q + 2]; o.w = r[4 * q + 3];
            orow[q] = o;
        }
        uint4* ob = reinterpret_cast<uint4*>(outhf) + (long long)node * 4;
#pragma unroll
        for (int g = 0; g < 4; g++) {
            uint4 p;
            p.x = pk2(r[8 * g + 0], r[8 * g + 1]);
            p.y = pk2(r[8 * g + 2], r[8 * g + 3]);
            p.z = pk2(r[8 * g + 4], r[8 * g + 5]);
            p.w = pk2(r[8 * g + 6], r[8 * g + 7]);
            ob[g] = p;
        }
    } else {
#pragma unroll
        for (int j = 0; j < 32; j++) r[j] = 0.f;
    }

    int lane = tid & 63, wid = tid >> 6;
#pragma unroll
    for (int j = 0; j < 32; j++) {
        float v = r[j], v2 = v * v;
#pragma unroll
        for (int off = 32; off >= 1; off >>= 1) {
            v += __shfl_down(v, off, 64);
            v2 += __shfl_down(v2, off, 64);
        }
        if (lane == 0) { sSum[wid * 32 + j] = v; sSq[wid * 32 + j] = v2; }
    }
    __syncthreads();
    if (tid < 32) {
        float a = sSum[tid] + sSum[32 + tid] + sSum[64 + tid] + sSum[96 + tid];
        float b = sSq[tid] + sSq[32 + tid] + sSq[64 + tid] + sSq[96 + tid];
        atomicAdd(&stats[tid], a);
        atomicAdd(&stats[32 + tid], b);
    }
}

// ============ layers 2-5 MLP with fused input BN, in-place h update + fp16 copy ============
__global__ __launch_bounds__(256) void mlp32_bn_k(float* __restrict__ h,
                                                  unsigned* __restrict__ hhf,
                                                  const float* __restrict__ agg,
                                                  const float* __restrict__ wa,
                                                  const float* __restrict__ ba,
                                                  const float* __restrict__ wb,
                                                  const float* __restrict__ bb,
                                                  const float* __restrict__ st,
                                                  const float* __restrict__ gamma,
                                                  const float* __restrict__ beta,
                                                  float* __restrict__ statsOut) {
    __shared__ float sWa[32 * 32];
    __shared__ float sWb[32 * 32];
    __shared__ float sBa[32], sBb[32];
    __shared__ float sSc[32], sSh[32];
    __shared__ float sSum[4 * 32], sSq[4 * 32];
    int tid = threadIdx.x;
    for (int i = tid; i < 32 * 32; i += 256) { sWa[i] = wa[i]; sWb[i] = wb[i]; }
    if (tid < 32) {
        sBa[tid] = ba[tid]; sBb[tid] = bb[tid];
        const float invn = 1.0f / NN;
        float mu = st[tid] * invn;
        float var = st[32 + tid] * invn - mu * mu;
        float scale = rsqrtf(var + BN_EPS) * gamma[tid];
        sSc[tid] = scale;
        sSh[tid] = beta[tid] - mu * scale;
    }
    __syncthreads();

    int node = blockIdx.x * 256 + tid;
    float r[32];
    if (node < NN) {
        float t[32];
#pragma unroll
        for (int j = 0; j < 32; j++) t[j] = sBa[j];
        const float4* hr = reinterpret_cast<const float4*>(h + (long long)node * 32);
        const float4* ar = reinterpret_cast<const float4*>(agg + (long long)node * 32);
        const float4* w4 = reinterpret_cast<const float4*>(sWa);
        for (int k4 = 0; k4 < 8; k4++) {
            float4 xv = hr[k4];
            float4 av = ar[k4];
            int kb = k4 * 4;
            float a0 = xv.x * sSc[kb + 0] + sSh[kb + 0] + av.x;
            float a1 = xv.y * sSc[kb + 1] + sSh[kb + 1] + av.y;
            float a2 = xv.z * sSc[kb + 2] + sSh[kb + 2] + av.z;
            float a3 = xv.w * sSc[kb + 3] + sSh[kb + 3] + av.w;
#pragma unroll
            for (int q = 0; q < 8; q++) {
                float4 w0 = w4[(kb + 0) * 8 + q];
                float4 w1 = w4[(kb + 1) * 8 + q];
                float4 w2 = w4[(kb + 2) * 8 + q];
                float4 w3 = w4[(kb + 3) * 8 + q];
                t[4 * q + 0] += a0 * w0.x + a1 * w1.x + a2 * w2.x + a3 * w3.x;
                t[4 * q + 1] += a0 * w0.y + a1 * w1.y + a2 * w2.y + a3 * w3.y;
                t[4 * q + 2] += a0 * w0.z + a1 * w1.z + a2 * w2.z + a3 * w3.z;
                t[4 * q + 3] += a0 * w0.w + a1 * w1.w + a2 * w2.w + a3 * w3.w;
            }
        }
#pragma unroll
        for (int j = 0; j < 32; j++) t[j] = fmaxf(t[j], 0.f);
#pragma unroll
        for (int j = 0; j < 32; j++) r[j] = sBb[j];
        const float4* v4 = reinterpret_cast<const float4*>(sWb);
        for (int k = 0; k < 32; k++) {
            float a = t[k];
#pragma unroll
            for (int q = 0; q < 8; q++) {
                float4 w = v4[k * 8 + q];
                r[4 * q + 0] += a * w.x;
                r[4 * q + 1] += a * w.y;
                r[4 * q + 2] += a * w.z;
                r[4 * q + 3] += a * w.w;
            }
        }
#pragma unroll
        for (int j = 0; j < 32; j++) r[j] = fmaxf(r[j], 0.f);
        float4* orow = reinterpret_cast<float4*>(h + (long long)node * 32);
#pragma unroll
        for (int q = 0; q < 8; q++) {
            float4 o;
            o.x = r[4 * q]; o.y = r[4 * q + 1]; o.z = r[4 * q + 2]; o.w = r[4 * q + 3];
            orow[q] = o;
        }
        uint4* ob = reinterpret_cast<uint4*>(hhf) + (long long)node * 4;
#pragma unroll
        for (int g = 0; g < 4; g++) {
            uint4 p;
            p.x = pk2(r[8 * g + 0], r[8 * g + 1]);
            p.y = pk2(r[8 * g + 2], r[8 * g + 3]);
            p.z = pk2(r[8 * g + 4], r[8 * g + 5]);
            p.w = pk2(r[8 * g + 6], r[8 * g + 7]);
            ob[g] = p;
        }
    } else {
#pragma unroll
        for (int j = 0; j < 32; j++) r[j] = 0.f;
    }

    int lane = tid & 63, wid = tid >> 6;
#pragma unroll
    for (int j = 0; j < 32; j++) {
        float v = r[j], v2 = v * v;
#pragma unroll
        for (int off = 32; off >= 1; off >>= 1) {
            v += __shfl_down(v, off, 64);
            v2 += __shfl_down(v2, off, 64);
        }
        if (lane == 0) { sSum[wid * 32 + j] = v; sSq[wid * 32 + j] = v2; }
    }
    __syncthreads();
    if (tid < 32) {
        float a = sSum[tid] + sSum[32 + tid] + sSum[64 + tid] + sSum[96 + tid];
        float b = sSq[tid] + sSq[32 + tid] + sSq[64 + tid] + sSq[96 + tid];
        atomicAdd(&statsOut[tid], a);
        atomicAdd(&statsOut[32 + tid], b);
    }
}

// ============ pool with fused BN of layer 5, privatized atomics ============
#define POOL_NPB 512
__global__ __launch_bounds__(256) void pool_bn_k(const float* __restrict__ h,
                                                 const int* __restrict__ batch,
                                                 const float* __restrict__ st,
                                                 const float* __restrict__ gamma,
                                                 const float* __restrict__ beta,
                                                 float* __restrict__ pooled) {
    int tid = threadIdx.x;
    int f = tid & 31;
    int p = tid >> 5;
    int n0 = blockIdx.x * POOL_NPB + p * (POOL_NPB / 8);
    int n1 = n0 + POOL_NPB / 8;
    if (n1 > NN) n1 = NN;
    if (n0 >= NN) return;
    const float invn = 1.0f / NN;
    float mu = st[f] * invn;
    float var = st[32 + f] * invn - mu * mu;
    float sc = rsqrtf(var + BN_EPS) * gamma[f];
    float sh = beta[f] - mu * sc;
    float acc = 0.f;
    int cur = batch[n0];
    for (int n = n0; n < n1; n++) {
        int g = batch[n];
        if (g != cur) {
            atomicAdd(&pooled[cur * 32 + f], acc);
            cur = g;
            acc = 0.f;
        }
        acc += h[(long long)n * 32 + f] * sc + sh;
    }
    atomicAdd(&pooled[cur * 32 + f], acc);
}

// ============ final FCs ============
__global__ __launch_bounds__(64) void final_k(const float* __restrict__ pooled,
                                              const float* __restrict__ w1,
                                              const float* __restrict__ b1,
                                              const float* __restrict__ w2,
                                              const float* __restrict__ b2,
                                              float* __restrict__ out) {
    int g = threadIdx.x;
    if (g >= NG) return;
    float t[32];
#pragma unroll
    for (int j = 0; j < 32; j++) t[j] = b1[j];
    for (int k = 0; k < 32; k++) {
        float a = pooled[g * 32 + k];
#pragma unroll
        for (int j = 0; j < 32; j++) t[j] += a * w1[k * 32 + j];
    }
#pragma unroll
    for (int j = 0; j < 32; j++) t[j] = fmaxf(t[j], 0.f);
    for (int c = 0; c < NC; c++) {
        float o = b2[c];
#pragma unroll
        for (int k = 0; k < 32; k++) o += t[k] * w2[k * NC + c];
        out[g * NC + c] = o;
    }
}

extern "C" void kernel_launch(void* const* d_in, const int* in_sizes, int n_in,
                              void* d_out, int out_size, void* d_ws, size_t ws_size,
                              hipStream_t stream) {
    const float* x = (const float*)d_in[0];
    const int* ei = (const int*)d_in[1];
    const int* batch = (const int*)d_in[2];
    const float* w1a = (const float*)d_in[3];
    const float* b1a = (const float*)d_in[4];
    const float* w1b = (const float*)d_in[5];
    const float* b1b = (const float*)d_in[6];
    const float* Wa = (const float*)d_in[7];
    const float* Ba = (const float*)d_in[8];
    const float* Wb = (const float*)d_in[9];
    const float* Bb = (const float*)d_in[10];
    const float* bn_gamma = (const float*)d_in[11];
    const float* bn_beta = (const float*)d_in[12];
    const float* fc1w = (const float*)d_in[13];
    const float* fc1b = (const float*)d_in[14];
    const float* fc2w = (const float*)d_in[15];
    const float* fc2b = (const float*)d_in[16];
    float* out = (float*)d_out;

    float* ws = (float*)d_ws;
    float* y = ws;                                    // NN*32 f32
    float* hb = y + (size_t)NN * 32;                  // NN*32 f32
    float* agg = hb + (size_t)NN * 32;                // NN*32 f32
    float* stats_all = agg + (size_t)NN * 32;         // 5*64
    float* pooled = stats_all + 5 * 64;               // NG*32
    unsigned* yhf = (unsigned*)(pooled + NG * 32);    // NN*16 uints (32 fp16/row) — 16B aligned
    unsigned* hbhf = yhf + (size_t)NN * 16;           // NN*16 uints
    unsigned* binned = hbhf + (size_t)NN * 16;        // NE
    int* bcnt = (int*)(binned + NE);                  // NBUCK
    int* bbase = bcnt + NBUCK;                        // NBUCK+1
    int* bcur = bbase + NBUCK + 1;                    // NBUCK
    int* rowptr = bcur + NBUCK;                       // NN+1
    int* csr = rowptr + NN + 1;                       // NE

    const int nodeBlocks = (NN + 255) / 256;
    const int gBlocks = (NN + 63) / 64;

    // ---- CSR build (bucketed, packed) ----
    hipMemsetAsync(bcnt, 0, NBUCK * sizeof(int), stream);
    binA_k<<<NCH, 256, 0, stream>>>(ei, bcnt);
    binB_k<<<1, 512, 0, stream>>>(bcnt, bbase, bcur);
    binC_k<<<NCH, 256, 0, stream>>>(ei, bcur, binned);
    binD_k<<<NBUCK, 256, 0, stream>>>(binned, bbase, rowptr, csr);

    // ---- layer 1: y = x@Wa (+fp16 copy, zeroes stats/pooled); gather fp16; tail MLP ----
    pre1_k<<<nodeBlocks, 256, 0, stream>>>(x, w1a, y, yhf, stats_all);
    gatherH_k<false><<<gBlocks, 256, 0, stream>>>(yhf, rowptr, csr, agg,
                                                  nullptr, nullptr, nullptr);
    mlp1b_k<<<nodeBlocks, 256, 0, stream>>>(y, agg, b1a, w1b, b1b, hb, hbhf, stats_all);

    // ---- layers 2-5 (32 feat), BN fused into consumers, fp16 gather ----
    for (int i = 0; i < 4; i++) {
        const float* st = stats_all + i * 64;
        const float* g = bn_gamma + i * 32;
        const float* be = bn_beta + i * 32;
        gatherH_k<true><<<gBlocks, 256, 0, stream>>>(hbhf, rowptr, csr, agg, st, g, be);
        mlp32_bn_k<<<nodeBlocks, 256, 0, stream>>>(hb, hbhf, agg, Wa + i * 1024, Ba + i * 32,
                                                   Wb + i * 1024, Bb + i * 32,
                                                   st, g, be, stats_all + (i + 1) * 64);
    }

    // ---- pool (BN5 fused) + FCs ----
    pool_bn_k<<<(NN + POOL_NPB - 1) / POOL_NPB, 256, 0, stream>>>(
        hb, batch, stats_all + 4 * 64, bn_gamma + 4 * 32, bn_beta + 4 * 32, pooled);
    final_k<<<1, 64, 0, stream>>>(pooled, fc1w, fc1b, fc2w, fc2b, out);
}